// Round 14
// baseline (296.872 us; speedup 1.0000x reference)
//
#include <hip/hip_runtime.h>
#include <hip/hip_bf16.h>
#include <math.h>

// ---------------------------------------------------------------------------
// WNO1d. wave_conv(v) = v + Syn(W1*lo8-lo8, W2*hi8-hi8)  (perfect reconstruction;
// intermediate highs pass through). Constant operators, computed on device:
//   A  (28x1024 analysis)  -> split-bf16 planes Ahi/Alo [32][1024] (pad rows 0)
//   M^T(28x1024 synthesis) -> split-bf16 planes MThi/MTlo [1024][32] (pad 0)
// Activations as split-bf16 planes vhi/vlo [b][s][c]. All GEMMs on MFMA
// (split-bf16 3-mfma = fp32-grade).
// Round 14: layer/head re-split for 2x wave parallelism: 128-thread blocks
// (2 waves per 64-s tile, each wave owns a 32-o half), grid 2048 -> 4096 waves
// (16/CU target, launch_bounds(128,3)). Layer barrier-free (proj reads own
// wave's c-half); head keeps one barrier (fc1 needs all c).
// ---------------------------------------------------------------------------

#define BDIM 64
#define SLEN 1024
#define WCH  64
#define BC   (BDIM*WCH)
#define NT   16         // 64-s proj tiles per batch

typedef short s16x8 __attribute__((ext_vector_type(8)));
typedef float f32x4 __attribute__((ext_vector_type(4)));

constexpr float RLv[12] = {
    0.11154074335008017f, 0.4946238903983854f, 0.7511339080215775f,
    0.3152503517092432f, -0.22626469396516913f, -0.12976686756709563f,
    0.09750160558707936f, 0.02752286553001629f, -0.031582039318031156f,
    0.0005538422009938016f, 0.004777257511010651f, -0.00107730108499558f };
constexpr float AHv[12] = {
     RLv[11], -RLv[10],  RLv[9], -RLv[8],  RLv[7], -RLv[6],
     RLv[5],  -RLv[4],   RLv[3], -RLv[2],  RLv[1], -RLv[0] };
constexpr float SLv[12] = {
     RLv[11], RLv[10], RLv[9], RLv[8], RLv[7], RLv[6],
     RLv[5],  RLv[4],  RLv[3], RLv[2], RLv[1], RLv[0] };
constexpr float SHv[12] = {
    -RLv[0],  RLv[1], -RLv[2],  RLv[3], -RLv[4],  RLv[5],
    -RLv[6],  RLv[7], -RLv[8],  RLv[9], -RLv[10], RLv[11] };

__device__ __forceinline__ float gelu_f(float x) {
    return 0.5f * x * (1.0f + erff(x * 0.7071067811865476f));
}
__device__ __forceinline__ unsigned short f2bf(float f) {
    __hip_bfloat16 h = __float2bfloat16(f);
    union { __hip_bfloat16 h; unsigned short u; } cv; cv.h = h; return cv.u;
}
__device__ __forceinline__ float bf2f(unsigned short u) {
    union { unsigned short u; __hip_bfloat16 h; } cv; cv.u = u;
    return __bfloat162float(cv.h);
}

// swizzled [c][s] plane (64x64 shorts): 16B blocks XORed -> aligned b128 frags
__device__ __forceinline__ int swz(int c, int s) {
    return c * 64 + ((((s >> 3) ^ (c & 7)) << 3) | (s & 7));
}
// swizzled [s][c] plane
__device__ __forceinline__ int swz2(int s, int c) {
    return s * 64 + ((((c >> 3) ^ (s & 7)) << 3) | (c & 7));
}

// ---------------------------------------------------------------------------
// precompute A (blocks 0..255) and M (blocks 256..283), split-bf16 planes.
// ---------------------------------------------------------------------------
__global__ __launch_bounds__(256) void precompute_kernel(
    unsigned short* __restrict__ Ahi, unsigned short* __restrict__ Alo,
    unsigned short* __restrict__ MThi, unsigned short* __restrict__ MTlo)
{
    __shared__ float A[4][1024];
    __shared__ float Bf[4][520];
    __shared__ float hib[14];
    const int t = threadIdx.x;

    if (blockIdx.x < 256) {
        const int l = t & 63;
        const int g = t >> 6;
        const int s0 = blockIdx.x * 4 + g;

        for (int i = l; i < SLEN; i += 64) A[g][i] = (i == s0) ? 1.0f : 0.0f;
        __syncthreads();

        const int NIN[8]  = {1024, 517, 264, 137, 74, 42, 26, 18};
        const int NOUT[8] = { 517, 264, 137,  74, 42, 26, 18, 14};

#pragma unroll
        for (int lev = 0; lev < 8; ++lev) {
            float* in  = (lev & 1) ? Bf[g] : A[g];
            float* out = (lev & 1) ? A[g] : Bf[g];
            const int nin = NIN[lev], nout = NOUT[lev];
            for (int m = l; m < nout; m += 64) {
                float alo = 0.f, ahi = 0.f;
#pragma unroll
                for (int tt = 0; tt < 12; ++tt) {
                    int jj = 2 * m + tt - 10;
                    if (jj < 0)         jj = -1 - jj;
                    else if (jj >= nin) jj = 2 * nin - 1 - jj;
                    float xv = in[jj];
                    alo += xv * RLv[tt];
                    if (lev == 7) ahi += xv * AHv[tt];
                }
                out[m] = alo;
                if (lev == 7) {
                    unsigned short h1 = f2bf(alo);
                    Ahi[m * SLEN + s0] = h1;
                    Alo[m * SLEN + s0] = f2bf(alo - bf2f(h1));
                    unsigned short h2 = f2bf(ahi);
                    Ahi[(14 + m) * SLEN + s0] = h2;
                    Alo[(14 + m) * SLEN + s0] = f2bf(ahi - bf2f(h2));
                }
            }
            __syncthreads();
        }
        if (l < 4) {
            Ahi[(28 + l) * SLEN + s0] = 0; Alo[(28 + l) * SLEN + s0] = 0;
            MThi[s0 * 32 + 28 + l] = 0;    MTlo[s0 * 32 + 28 + l] = 0;
        }
        return;
    }

    const int u = blockIdx.x - 256;     // 0..27
    float* Af = A[0];
    float* Bff = Bf[0];
    if (t < 14) {
        Af[t]  = (u < 14 && t == u) ? 1.0f : 0.0f;
        hib[t] = (u >= 14 && t == (u - 14)) ? 1.0f : 0.0f;
    }
    __syncthreads();

    const int NH[8] = {14, 18, 26, 42, 74, 137, 264, 517};
    const int NO[8] = {18, 26, 42, 74, 138, 264, 518, 1024};

#pragma unroll
    for (int s = 0; s < 8; ++s) {
        const float* lo = (s & 1) ? Bff : Af;
        float* out      = (s & 1) ? Af : Bff;
        const int N = NH[s], nout = NO[s];
        for (int m = t; m < nout; m += 256) {
            float acc = 0.f;
#pragma unroll
            for (int tt = 0; tt < 12; ++tt) {
                int uu = m + tt - 1;
                if ((uu & 1) == 0) {
                    int q = uu >> 1;
                    if (q < N) {
                        acc += lo[q] * SLv[tt];
                        if (s == 0) acc += hib[q] * SHv[tt];
                    }
                }
            }
            out[m] = acc;
        }
        __syncthreads();
    }
    for (int m = t; m < SLEN; m += 256) {
        float f = Af[m];
        unsigned short h = f2bf(f);
        MThi[m * 32 + u] = h;
        MTlo[m * 32 + u] = f2bf(f - bf2f(h));
    }
}

// ---------------------------------------------------------------------------
// proj-MFMA body for barrier-style 64-s blocks (fc0proj only, 256 threads).
// ---------------------------------------------------------------------------
__device__ __forceinline__ void proj_mfma(
    const unsigned short* Phi, const unsigned short* Plo,
    const unsigned short* __restrict__ Ahi, const unsigned short* __restrict__ Alo,
    float* __restrict__ Ppart, int bb, int tile, int s0, int t)
{
    const int lane = t & 63;
    const int w    = t >> 6;
    const int qr   = lane >> 4;
    const int ln   = lane & 15;
    const int mt   = w >> 1;
    const int nb   = (w & 1) * 2;

    f32x4 acc[2];
    acc[0] = (f32x4){0.f,0.f,0.f,0.f};
    acc[1] = (f32x4){0.f,0.f,0.f,0.f};

#pragma unroll
    for (int kk = 0; kk < 2; ++kk) {
        const int k0 = kk * 32;
        const int arow = (mt * 16 + ln) * SLEN + s0 + k0 + qr * 8;
        s16x8 ah = *(const s16x8*)&Ahi[arow];
        s16x8 al = *(const s16x8*)&Alo[arow];
        const int bk = (k0 >> 3) + qr;
#pragma unroll
        for (int ni = 0; ni < 2; ++ni) {
            const int c = (nb + ni) * 16 + ln;
            const int boff = c * 64 + (((bk ^ (c & 7)) << 3));
            s16x8 bh = *(const s16x8*)&Phi[boff];
            s16x8 bl = *(const s16x8*)&Plo[boff];
            acc[ni] = __builtin_amdgcn_mfma_f32_16x16x32_bf16(ah, bh, acc[ni], 0, 0, 0);
            acc[ni] = __builtin_amdgcn_mfma_f32_16x16x32_bf16(al, bh, acc[ni], 0, 0, 0);
            acc[ni] = __builtin_amdgcn_mfma_f32_16x16x32_bf16(ah, bl, acc[ni], 0, 0, 0);
        }
    }
#pragma unroll
    for (int ni = 0; ni < 2; ++ni) {
#pragma unroll
        for (int r = 0; r < 4; ++r) {
            int xr = mt * 16 + qr * 4 + r;
            if (xr < 28) {
                int c = (nb + ni) * 16 + ln;
                Ppart[((size_t)(bb * NT + tile) * 28 + xr) * 64 + c] = acc[ni][r];
            }
        }
    }
}

// ---------------------------------------------------------------------------
// fc0 + proj0 + prep, one dispatch (unchanged).
// ---------------------------------------------------------------------------
__global__ __launch_bounds__(256, 4) void fc0proj_kernel(
    const float* __restrict__ x,
    const float* __restrict__ fc0w_0, const float* __restrict__ fc0b_0,
    const float* __restrict__ fc0w_1, const float* __restrict__ fc0b_1,
    const float* __restrict__ fc1w_0, const float* __restrict__ fc1w_1,
    const unsigned short* __restrict__ Ahi, const unsigned short* __restrict__ Alo,
    unsigned short* __restrict__ vhi0, unsigned short* __restrict__ vlo0,
    unsigned short* __restrict__ vhi1, unsigned short* __restrict__ vlo1,
    unsigned short* __restrict__ w1hi, unsigned short* __restrict__ w1lo,
    unsigned short* __restrict__ Dhi,  unsigned short* __restrict__ Dlo,
    float* __restrict__ Ppart)
{
    const int t = threadIdx.x;
    if (blockIdx.x >= 2048) {
        const int gid = (blockIdx.x - 2048) * 256 + t;
        for (int idx = gid; idx < 16384; idx += 2048) {
            int br = idx >> 13, r = idx & 8191;
            int h = r >> 6, c = r & 63;
            float f = (br ? fc1w_1 : fc1w_0)[c * 128 + h];
            unsigned short hh = f2bf(f);
            w1hi[idx] = hh;
            w1lo[idx] = f2bf(f - bf2f(hh));
        }
        for (int idx = gid; idx < 32768; idx += 2048) {
            int bb = idx >> 8, o = (idx >> 2) & 63, j = idx & 3;
            Dhi[bb * 2048 + o * 32 + 28 + j] = 0;
            Dlo[bb * 2048 + o * 32 + 28 + j] = 0;
        }
        return;
    }

    __shared__ unsigned short Phi[4096];
    __shared__ unsigned short Plo[4096];
    const int bb   = blockIdx.x >> 4;
    const int tile = blockIdx.x & 15;
    const int br = bb >> 6, b = bb & 63;
    const int s0 = tile << 6;
    const float* fc0w = br ? fc0w_1 : fc0w_0;
    const float* fc0b = br ? fc0b_1 : fc0b_0;
    unsigned short* vhi = br ? vhi1 : vhi0;
    unsigned short* vlo = br ? vlo1 : vlo0;
    const size_t base = ((size_t)b * SLEN + s0) * 64;

    for (int idx = t; idx < 4096; idx += 256) {
        int s = idx >> 6, c = idx & 63;
        float val = x[b * SLEN + s0 + s] * fc0w[c]
                  + (float)(s0 + s) * (1.0f / 1023.0f) * fc0w[WCH + c] + fc0b[c];
        unsigned short h = f2bf(val);
        unsigned short l = f2bf(val - bf2f(h));
        vhi[base + idx] = h;
        vlo[base + idx] = l;
        int a = swz(c, s);
        Phi[a] = h;
        Plo[a] = l;
    }
    __syncthreads();
    proj_mfma(Phi, Plo, Ahi, Alo, Ppart, bb, tile, s0, t);
}

// ---------------------------------------------------------------------------
// Mix (per layer) — unchanged.
// ---------------------------------------------------------------------------
__global__ __launch_bounds__(256) void mix_kernel(
    const float* __restrict__ Ppart,
    const float* __restrict__ w1_0, const float* __restrict__ w2_0,
    const float* __restrict__ w1_1, const float* __restrict__ w2_1,
    const float* __restrict__ cw_0, const float* __restrict__ cw_1,
    unsigned short* __restrict__ cwPhi, unsigned short* __restrict__ cwPlo,
    unsigned short* __restrict__ Dhi, unsigned short* __restrict__ Dlo)
{
    const int t = threadIdx.x;
    const int br  = blockIdx.x / 225;
    const int sub = blockIdx.x % 225;

    if (sub == 224) {
        const float* cw = br ? cw_1 : cw_0;
        for (int idx = t; idx < 4096; idx += 256) {
            int k = idx >> 6, o = idx & 63;
            float val = cw[o * 64 + k] + ((k == o) ? 1.0f : 0.0f);
            unsigned short h = f2bf(val);
            cwPhi[br * 4096 + o * 64 + k] = h;
            cwPlo[br * 4096 + o * 64 + k] = f2bf(val - bf2f(h));
        }
        return;
    }

    __shared__ float Ws[64][65];
    __shared__ float LO[8][64];
    const int o = t & 63;
    const int w = t >> 6;
    const int x  = sub >> 3;
    const int b0 = (sub & 7) << 3;

    const float* wbase = (x < 14) ? (br ? w1_1 : w1_0) : (br ? w2_1 : w2_0);
    const int xi = (x < 14) ? x : (x - 14);
    for (int idx = t; idx < 4096; idx += 256)
        Ws[idx >> 6][idx & 63] = wbase[(size_t)idx * 14 + xi];

#pragma unroll
    for (int j = 0; j < 2; ++j) {
        int bi = w + 4 * j;
        int bb = br * 64 + b0 + bi;
        float s = 0.f;
        for (int tile = 0; tile < NT; ++tile)
            s += Ppart[((size_t)(bb * NT + tile) * 28 + x) * 64 + o];
        LO[bi][o] = s;
    }
    __syncthreads();

#pragma unroll
    for (int j = 0; j < 2; ++j) {
        int bi = w + 4 * j;
        int bb = br * 64 + b0 + bi;
        float acc = 0.f;
        for (int i = 0; i < 64; ++i)
            acc += LO[bi][i] * Ws[i][o];
        acc -= LO[bi][o];
        unsigned short h = f2bf(acc);
        Dhi[bb * 2048 + o * 32 + x] = h;
        Dlo[bb * 2048 + o * 32 + x] = f2bf(acc - bf2f(h));
    }
}

// ---------------------------------------------------------------------------
// Fused layer (i = 0,1,2): 128-thread blocks, 2 waves per 64-s tile, each wave
// owns a 32-o half. B frags register-resident; proj reads only own wave's
// c-half -> NO barriers at all. grid = br*1024 + b*16 + tile (2048 blocks).
// ---------------------------------------------------------------------------
__global__ __launch_bounds__(128, 3) void layer_kernel(
    const unsigned short* __restrict__ vhi0, const unsigned short* __restrict__ vlo0,
    const unsigned short* __restrict__ vhi1, const unsigned short* __restrict__ vlo1,
    unsigned short* __restrict__ ohi0, unsigned short* __restrict__ olo0,
    unsigned short* __restrict__ ohi1, unsigned short* __restrict__ olo1,
    const unsigned short* __restrict__ MThi, const unsigned short* __restrict__ MTlo,
    const unsigned short* __restrict__ Ahi,  const unsigned short* __restrict__ Alo,
    const unsigned short* __restrict__ cwPhi, const unsigned short* __restrict__ cwPlo,
    const unsigned short* __restrict__ Dhi,   const unsigned short* __restrict__ Dlo,
    const float* __restrict__ cb_0, const float* __restrict__ cb_1,
    float* __restrict__ Ppart)
{
    __shared__ unsigned short Phi[4096];   // block-shared swizzled [c][s64]
    __shared__ unsigned short Plo[4096];

    const int t = threadIdx.x;
    const int bid = blockIdx.x;
    const int br  = bid >> 10;
    const int rem = bid & 1023;
    const int b    = rem >> 4;
    const int tile = rem & 15;
    const int s0   = tile << 6;
    const size_t bS = (size_t)b * SLEN;
    const unsigned short* vhi = br ? vhi1 : vhi0;
    const unsigned short* vlo = br ? vlo1 : vlo0;
    unsigned short* ohi = br ? ohi1 : ohi0;
    unsigned short* olo = br ? olo1 : olo0;
    const float* cb = br ? cb_1 : cb_0;
    const int bb = br * 64 + b;

    const int lane = t & 63;
    const int w    = t >> 6;          // 0..1: o-half
    const int qr   = lane >> 4;
    const int ln   = lane & 15;

    // ---- preload B fragments for this wave's o-half ----
    s16x8 Bh[2][2], Bl[2][2];
#pragma unroll
    for (int kk = 0; kk < 2; ++kk)
#pragma unroll
        for (int ni = 0; ni < 2; ++ni) {
            const int o = w * 32 + ni * 16 + ln;
            const int boff = br * 4096 + o * 64 + kk * 32 + qr * 8;
            Bh[kk][ni] = *(const s16x8*)&cwPhi[boff];
            Bl[kk][ni] = *(const s16x8*)&cwPlo[boff];
        }
    s16x8 Dhf[2], Dlf[2];
#pragma unroll
    for (int ni = 0; ni < 2; ++ni) {
        const int o = w * 32 + ni * 16 + ln;
        const int boff = bb * 2048 + o * 32 + qr * 8;
        Dhf[ni] = *(const s16x8*)&Dhi[boff];
        Dlf[ni] = *(const s16x8*)&Dlo[boff];
    }
    float cbv[2];
#pragma unroll
    for (int ni = 0; ni < 2; ++ni) cbv[ni] = cb[w * 32 + ni * 16 + ln];

    // ---- 4 m-tiles (both waves iterate all 64 s, each its own o-half) ----
#pragma unroll
    for (int mi = 0; mi < 4; ++mi) {
        const int srow = mi * 16 + ln;
        f32x4 acc[2];
        acc[0] = (f32x4){0.f,0.f,0.f,0.f};
        acc[1] = (f32x4){0.f,0.f,0.f,0.f};

#pragma unroll
        for (int kk = 0; kk < 2; ++kk) {
            const size_t aoff = (bS + s0 + srow) * 64 + kk * 32 + qr * 8;
            s16x8 ah = *(const s16x8*)&vhi[aoff];
            s16x8 al = *(const s16x8*)&vlo[aoff];
#pragma unroll
            for (int ni = 0; ni < 2; ++ni) {
                acc[ni] = __builtin_amdgcn_mfma_f32_16x16x32_bf16(ah, Bh[kk][ni], acc[ni], 0, 0, 0);
                acc[ni] = __builtin_amdgcn_mfma_f32_16x16x32_bf16(al, Bh[kk][ni], acc[ni], 0, 0, 0);
                acc[ni] = __builtin_amdgcn_mfma_f32_16x16x32_bf16(ah, Bl[kk][ni], acc[ni], 0, 0, 0);
            }
        }
        {
            const size_t aoff = (size_t)(s0 + srow) * 32 + qr * 8;
            s16x8 ah = *(const s16x8*)&MThi[aoff];
            s16x8 al = *(const s16x8*)&MTlo[aoff];
#pragma unroll
            for (int ni = 0; ni < 2; ++ni) {
                acc[ni] = __builtin_amdgcn_mfma_f32_16x16x32_bf16(ah, Dhf[ni], acc[ni], 0, 0, 0);
                acc[ni] = __builtin_amdgcn_mfma_f32_16x16x32_bf16(al, Dhf[ni], acc[ni], 0, 0, 0);
                acc[ni] = __builtin_amdgcn_mfma_f32_16x16x32_bf16(ah, Dlf[ni], acc[ni], 0, 0, 0);
            }
        }
        // epilogue: gelu, split, global + LDS (own c-half only)
#pragma unroll
        for (int ni = 0; ni < 2; ++ni) {
            const int o = w * 32 + ni * 16 + ln;
#pragma unroll
            for (int r = 0; r < 4; ++r) {
                const int sl64 = mi * 16 + qr * 4 + r;
                float val = gelu_f(acc[ni][r] + cbv[ni]);
                unsigned short h = f2bf(val);
                unsigned short l = f2bf(val - bf2f(h));
                const size_t go = (bS + s0 + sl64) * 64 + o;
                ohi[go] = h;
                olo[go] = l;
                const int a = swz(o, sl64);
                Phi[a] = h;
                Plo[a] = l;
            }
        }
    }

    // ---- proj on own c-half (same-wave LDS RAW: no barrier needed) ----
    f32x4 pacc[2][2];
#pragma unroll
    for (int mt = 0; mt < 2; ++mt)
#pragma unroll
        for (int ni = 0; ni < 2; ++ni) pacc[mt][ni] = (f32x4){0.f,0.f,0.f,0.f};

#pragma unroll
    for (int kk = 0; kk < 2; ++kk) {
        const int bk = kk * 4 + qr;
        s16x8 pah[2], pal[2];
#pragma unroll
        for (int mt = 0; mt < 2; ++mt) {
            const int arow = (mt * 16 + ln) * SLEN + s0 + kk * 32 + qr * 8;
            pah[mt] = *(const s16x8*)&Ahi[arow];
            pal[mt] = *(const s16x8*)&Alo[arow];
        }
#pragma unroll
        for (int ni = 0; ni < 2; ++ni) {
            const int c = w * 32 + ni * 16 + ln;
            const int boff = c * 64 + ((bk ^ (c & 7)) << 3);
            s16x8 bh = *(const s16x8*)&Phi[boff];
            s16x8 bl = *(const s16x8*)&Plo[boff];
#pragma unroll
            for (int mt = 0; mt < 2; ++mt) {
                pacc[mt][ni] = __builtin_amdgcn_mfma_f32_16x16x32_bf16(pah[mt], bh, pacc[mt][ni], 0, 0, 0);
                pacc[mt][ni] = __builtin_amdgcn_mfma_f32_16x16x32_bf16(pal[mt], bh, pacc[mt][ni], 0, 0, 0);
                pacc[mt][ni] = __builtin_amdgcn_mfma_f32_16x16x32_bf16(pah[mt], bl, pacc[mt][ni], 0, 0, 0);
            }
        }
    }
#pragma unroll
    for (int mt = 0; mt < 2; ++mt)
#pragma unroll
        for (int ni = 0; ni < 2; ++ni) {
            const int c = w * 32 + ni * 16 + ln;
#pragma unroll
            for (int r = 0; r < 4; ++r) {
                const int xr = mt * 16 + qr * 4 + r;
                if (xr < 28)
                    Ppart[((size_t)(bb * NT + tile) * 28 + xr) * 64 + c] = pacc[mt][ni][r];
            }
        }
}

// ---------------------------------------------------------------------------
// Head with fused layer 3: 128-thread blocks (2 waves per 64-s tile).
// Phase A: each wave computes its 32-o half of v' -> shared LDS (swz2 [s][c]),
// one __syncthreads (fc1 needs all c). Phase B: wave owns 64-h half of fc1,
// gelu*fc2, shfl-reduce, atomicAdd into memset-zeroed out (fc2b from wave 0).
// ---------------------------------------------------------------------------
__global__ __launch_bounds__(128, 3) void head_kernel(
    const unsigned short* __restrict__ vhi0, const unsigned short* __restrict__ vlo0,
    const unsigned short* __restrict__ vhi1, const unsigned short* __restrict__ vlo1,
    const unsigned short* __restrict__ MThi, const unsigned short* __restrict__ MTlo,
    const unsigned short* __restrict__ cwPhi, const unsigned short* __restrict__ cwPlo,
    const unsigned short* __restrict__ Dhi,   const unsigned short* __restrict__ Dlo,
    const float* __restrict__ cb_0, const float* __restrict__ cb_1,
    const unsigned short* __restrict__ w1hi, const unsigned short* __restrict__ w1lo,
    const float* __restrict__ fc1b_0, const float* __restrict__ fc2w_0,
    const float* __restrict__ fc2b_0,
    const float* __restrict__ fc1b_1, const float* __restrict__ fc2w_1,
    const float* __restrict__ fc2b_1,
    float* __restrict__ out)
{
    __shared__ unsigned short Vh[4096];    // block-shared swz2 [s64][c]
    __shared__ unsigned short Vl[4096];

    const int t = threadIdx.x;
    const int bid = blockIdx.x;
    const int br  = bid >> 10;
    const int rem = bid & 1023;
    const int b    = rem >> 4;
    const int tile = rem & 15;
    const int s0   = tile << 6;
    const size_t bS = (size_t)b * SLEN;

    const int lane = t & 63;
    const int w    = t >> 6;          // 0..1
    const int qr   = lane >> 4;
    const int ln   = lane & 15;

    const unsigned short* vhi = br ? vhi1 : vhi0;
    const unsigned short* vlo = br ? vlo1 : vlo0;
    const float* cb   = br ? cb_1 : cb_0;
    const float* fc1b = br ? fc1b_1 : fc1b_0;
    const float* fc2w = br ? fc2w_1 : fc2w_0;
    const float fc2b  = (br ? fc2b_1 : fc2b_0)[0];
    const int bb = br * 64 + b;

    // ---- phase A: layer-3, own 32-o half ----
    {
        s16x8 Bh[2][2], Bl[2][2];
#pragma unroll
        for (int kk = 0; kk < 2; ++kk)
#pragma unroll
            for (int ni = 0; ni < 2; ++ni) {
                const int o = w * 32 + ni * 16 + ln;
                const int boff = br * 4096 + o * 64 + kk * 32 + qr * 8;
                Bh[kk][ni] = *(const s16x8*)&cwPhi[boff];
                Bl[kk][ni] = *(const s16x8*)&cwPlo[boff];
            }
        s16x8 Dhf[2], Dlf[2];
#pragma unroll
        for (int ni = 0; ni < 2; ++ni) {
            const int o = w * 32 + ni * 16 + ln;
            const int boff = bb * 2048 + o * 32 + qr * 8;
            Dhf[ni] = *(const s16x8*)&Dhi[boff];
            Dlf[ni] = *(const s16x8*)&Dlo[boff];
        }
        float cbv[2];
#pragma unroll
        for (int ni = 0; ni < 2; ++ni) cbv[ni] = cb[w * 32 + ni * 16 + ln];

#pragma unroll
        for (int mi = 0; mi < 4; ++mi) {
            const int srow = mi * 16 + ln;
            f32x4 acc[2];
            acc[0] = (f32x4){0.f,0.f,0.f,0.f};
            acc[1] = (f32x4){0.f,0.f,0.f,0.f};

#pragma unroll
            for (int kk = 0; kk < 2; ++kk) {
                const size_t aoff = (bS + s0 + srow) * 64 + kk * 32 + qr * 8;
                s16x8 ah = *(const s16x8*)&vhi[aoff];
                s16x8 al = *(const s16x8*)&vlo[aoff];
#pragma unroll
                for (int ni = 0; ni < 2; ++ni) {
                    acc[ni] = __builtin_amdgcn_mfma_f32_16x16x32_bf16(ah, Bh[kk][ni], acc[ni], 0, 0, 0);
                    acc[ni] = __builtin_amdgcn_mfma_f32_16x16x32_bf16(al, Bh[kk][ni], acc[ni], 0, 0, 0);
                    acc[ni] = __builtin_amdgcn_mfma_f32_16x16x32_bf16(ah, Bl[kk][ni], acc[ni], 0, 0, 0);
                }
            }
            {
                const size_t aoff = (size_t)(s0 + srow) * 32 + qr * 8;
                s16x8 ah = *(const s16x8*)&MThi[aoff];
                s16x8 al = *(const s16x8*)&MTlo[aoff];
#pragma unroll
                for (int ni = 0; ni < 2; ++ni) {
                    acc[ni] = __builtin_amdgcn_mfma_f32_16x16x32_bf16(ah, Dhf[ni], acc[ni], 0, 0, 0);
                    acc[ni] = __builtin_amdgcn_mfma_f32_16x16x32_bf16(al, Dhf[ni], acc[ni], 0, 0, 0);
                    acc[ni] = __builtin_amdgcn_mfma_f32_16x16x32_bf16(ah, Dlf[ni], acc[ni], 0, 0, 0);
                }
            }
#pragma unroll
            for (int ni = 0; ni < 2; ++ni) {
                const int o = w * 32 + ni * 16 + ln;
#pragma unroll
                for (int r = 0; r < 4; ++r) {
                    const int sl64 = mi * 16 + qr * 4 + r;
                    float val = acc[ni][r] + cbv[ni];
                    unsigned short h = f2bf(val);
                    unsigned short l = f2bf(val - bf2f(h));
                    const int a = swz2(sl64, o);
                    Vh[a] = h;
                    Vl[a] = l;
                }
            }
        }
    }
    __syncthreads();

    // ---- phase B: fc1 GEMM, own 64-h half ----
    s16x8 Wh[2][4], Wl[2][4];
#pragma unroll
    for (int kk = 0; kk < 2; ++kk)
#pragma unroll
        for (int ni = 0; ni < 4; ++ni) {
            const int h = w * 64 + ni * 16 + ln;
            const int boff = br * 8192 + h * 64 + kk * 32 + qr * 8;
            Wh[kk][ni] = *(const s16x8*)&w1hi[boff];
            Wl[kk][ni] = *(const s16x8*)&w1lo[boff];
        }
    float b1v[4], w2v[4];
#pragma unroll
    for (int ni = 0; ni < 4; ++ni) {
        b1v[ni] = fc1b[w * 64 + ni * 16 + ln];
        w2v[ni] = fc2w[w * 64 + ni * 16 + ln];
    }

#pragma unroll
    for (int mi = 0; mi < 4; ++mi) {
        f32x4 acc1[4];
#pragma unroll
        for (int ni = 0; ni < 4; ++ni) acc1[ni] = (f32x4){0.f,0.f,0.f,0.f};

#pragma unroll
        for (int kk = 0; kk < 2; ++kk) {
            const int blk = kk * 4 + qr;
            const int sl  = mi * 16 + ln;
            const int a   = sl * 64 + ((blk ^ (sl & 7)) << 3);
            s16x8 ah = *(const s16x8*)&Vh[a];
            s16x8 al = *(const s16x8*)&Vl[a];
#pragma unroll
            for (int ni = 0; ni < 4; ++ni) {
                acc1[ni] = __builtin_amdgcn_mfma_f32_16x16x32_bf16(ah, Wh[kk][ni], acc1[ni], 0, 0, 0);
                acc1[ni] = __builtin_amdgcn_mfma_f32_16x16x32_bf16(al, Wh[kk][ni], acc1[ni], 0, 0, 0);
                acc1[ni] = __builtin_amdgcn_mfma_f32_16x16x32_bf16(ah, Wl[kk][ni], acc1[ni], 0, 0, 0);
            }
        }
        float partial[4] = {0.f, 0.f, 0.f, 0.f};
#pragma unroll
        for (int ni = 0; ni < 4; ++ni) {
#pragma unroll
            for (int r = 0; r < 4; ++r)
                partial[r] += gelu_f(acc1[ni][r] + b1v[ni]) * w2v[ni];
        }
#pragma unroll
        for (int r = 0; r < 4; ++r) {
            partial[r] += __shfl_xor(partial[r], 1, 64);
            partial[r] += __shfl_xor(partial[r], 2, 64);
            partial[r] += __shfl_xor(partial[r], 4, 64);
            partial[r] += __shfl_xor(partial[r], 8, 64);
        }
        if (ln == 0) {
            const float bias = (w == 0) ? fc2b : 0.f;
#pragma unroll
            for (int r = 0; r < 4; ++r)
                atomicAdd(&out[bS + s0 + mi * 16 + qr * 4 + r],
                          partial[r] + bias);
        }
    }
}

// ---------------------------------------------------------------------------
extern "C" void kernel_launch(void* const* d_in, const int* in_sizes, int n_in,
                              void* d_out, int out_size, void* d_ws, size_t ws_size,
                              hipStream_t stream)
{
    const float* x = (const float*)d_in[0];
    const float* P[2][10];
    for (int br = 0; br < 2; ++br)
        for (int k = 0; k < 10; ++k)
            P[br][k] = (const float*)d_in[1 + br * 10 + k];
    // order: fc0_w, fc0_b, wave_w1, wave_w2, cw, cb, fc1_w, fc1_b, fc2_w, fc2_b

    char* p = (char*)d_ws;
    const size_t PL = (size_t)BC * SLEN * 2;   // one short plane: 8.39 MB
    unsigned short* vplane[8];
    for (int i = 0; i < 8; ++i) { vplane[i] = (unsigned short*)p; p += PL; }
    unsigned short* Ahi  = (unsigned short*)p; p += 32 * SLEN * 2;
    unsigned short* Alo  = (unsigned short*)p; p += 32 * SLEN * 2;
    unsigned short* MThi = (unsigned short*)p; p += SLEN * 32 * 2;
    unsigned short* MTlo = (unsigned short*)p; p += SLEN * 32 * 2;
    float* Ppart = (float*)p;                  p += (size_t)128 * NT * 28 * 64 * 4;
    unsigned short* cwPhi = (unsigned short*)p; p += 2 * 4096 * 2;
    unsigned short* cwPlo = (unsigned short*)p; p += 2 * 4096 * 2;
    unsigned short* Dhi   = (unsigned short*)p; p += (size_t)128 * 2048 * 2;
    unsigned short* Dlo   = (unsigned short*)p; p += (size_t)128 * 2048 * 2;
    unsigned short* w1hi  = (unsigned short*)p; p += 2 * 8192 * 2;
    unsigned short* w1lo  = (unsigned short*)p; p += 2 * 8192 * 2;

    unsigned short *h0a = vplane[0], *l0a = vplane[1], *h0b = vplane[2], *l0b = vplane[3];
    unsigned short *h1a = vplane[4], *l1a = vplane[5], *h1b = vplane[6], *l1b = vplane[7];

    precompute_kernel<<<284, 256, 0, stream>>>(Ahi, Alo, MThi, MTlo);

    hipMemsetAsync(d_out, 0, (size_t)out_size * sizeof(float), stream);

    fc0proj_kernel<<<2056, 256, 0, stream>>>(
        x, P[0][0], P[0][1], P[1][0], P[1][1], P[0][6], P[1][6],
        Ahi, Alo, h0a, l0a, h1a, l1a, w1hi, w1lo, Dhi, Dlo, Ppart);

    for (int i = 0; i < 3; ++i) {
        mix_kernel<<<450, 256, 0, stream>>>(
            Ppart,
            P[0][2] + (size_t)i * WCH * WCH * 14, P[0][3] + (size_t)i * WCH * WCH * 14,
            P[1][2] + (size_t)i * WCH * WCH * 14, P[1][3] + (size_t)i * WCH * WCH * 14,
            P[0][4] + (size_t)i * WCH * WCH,      P[1][4] + (size_t)i * WCH * WCH,
            cwPhi, cwPlo, Dhi, Dlo);
        layer_kernel<<<2048, 128, 0, stream>>>(
            h0a, l0a, h1a, l1a,
            h0b, l0b, h1b, l1b,
            MThi, MTlo, Ahi, Alo, cwPhi, cwPlo, Dhi, Dlo,
            P[0][5] + (size_t)i * WCH, P[1][5] + (size_t)i * WCH,
            Ppart);
        unsigned short* tmp;
        tmp = h0a; h0a = h0b; h0b = tmp;  tmp = l0a; l0a = l0b; l0b = tmp;
        tmp = h1a; h1a = h1b; h1b = tmp;  tmp = l1a; l1a = l1b; l1b = tmp;
    }

    mix_kernel<<<450, 256, 0, stream>>>(
        Ppart,
        P[0][2] + (size_t)3 * WCH * WCH * 14, P[0][3] + (size_t)3 * WCH * WCH * 14,
        P[1][2] + (size_t)3 * WCH * WCH * 14, P[1][3] + (size_t)3 * WCH * WCH * 14,
        P[0][4] + (size_t)3 * WCH * WCH,      P[1][4] + (size_t)3 * WCH * WCH,
        cwPhi, cwPlo, Dhi, Dlo);

    head_kernel<<<2048, 128, 0, stream>>>(
        h0a, l0a, h1a, l1a,
        MThi, MTlo, cwPhi, cwPlo, Dhi, Dlo,
        P[0][5] + (size_t)3 * WCH, P[1][5] + (size_t)3 * WCH,
        w1hi, w1lo,
        P[0][7], P[0][8], P[0][9],
        P[1][7], P[1][8], P[1][9],
        (float*)d_out);
}

// Round 15
// 287.278 us; speedup vs baseline: 1.0334x; 1.0334x over previous
//
#include <hip/hip_runtime.h>
#include <hip/hip_bf16.h>
#include <math.h>

// ---------------------------------------------------------------------------
// WNO1d. wave_conv(v) = v + Syn(W1*lo8-lo8, W2*hi8-hi8)  (perfect reconstruction;
// intermediate highs pass through). Constant operators, computed on device:
//   A  (28x1024 analysis)  -> split-bf16 planes Ahi/Alo [32][1024] (pad rows 0)
//   M^T(28x1024 synthesis) -> split-bf16 planes MThi/MTlo [1024][32] (pad 0)
// Activations: PACKED split-bf16 planes v[b][s][c] as u32 = hi | lo<<16
// (one dword store per value, consumers unpack with v_perm). All GEMMs on MFMA
// (split-bf16 3-mfma = fp32-grade).
// Round 15: packed v planes (halve epilogue stores, better locality) + fast
// sigmoid-gelu (~9 VALU ops vs ~20 for erff; <=4e-4 deviation/application).
// ---------------------------------------------------------------------------

#define BDIM 64
#define SLEN 1024
#define WCH  64
#define BC   (BDIM*WCH)
#define NT   16         // 64-s proj tiles per batch

typedef short s16x8 __attribute__((ext_vector_type(8)));
typedef float f32x4 __attribute__((ext_vector_type(4)));

constexpr float RLv[12] = {
    0.11154074335008017f, 0.4946238903983854f, 0.7511339080215775f,
    0.3152503517092432f, -0.22626469396516913f, -0.12976686756709563f,
    0.09750160558707936f, 0.02752286553001629f, -0.031582039318031156f,
    0.0005538422009938016f, 0.004777257511010651f, -0.00107730108499558f };
constexpr float AHv[12] = {
     RLv[11], -RLv[10],  RLv[9], -RLv[8],  RLv[7], -RLv[6],
     RLv[5],  -RLv[4],   RLv[3], -RLv[2],  RLv[1], -RLv[0] };
constexpr float SLv[12] = {
     RLv[11], RLv[10], RLv[9], RLv[8], RLv[7], RLv[6],
     RLv[5],  RLv[4],  RLv[3], RLv[2], RLv[1], RLv[0] };
constexpr float SHv[12] = {
    -RLv[0],  RLv[1], -RLv[2],  RLv[3], -RLv[4],  RLv[5],
    -RLv[6],  RLv[7], -RLv[8],  RLv[9], -RLv[10], RLv[11] };

// fast gelu: 0.5x(1+tanh(.79788(x+.044715x^3))) = x * sigmoid(2z).
// |dev from erf-gelu| <= ~4e-4 per application; budget check in header comment.
__device__ __forceinline__ float gelu_f(float x) {
    float z = 0.7978845608f * (x + 0.044715f * x * x * x);
    return x / (1.0f + __expf(-2.0f * z));
}
__device__ __forceinline__ unsigned short f2bf(float f) {
    __hip_bfloat16 h = __float2bfloat16(f);
    union { __hip_bfloat16 h; unsigned short u; } cv; cv.h = h; return cv.u;
}
__device__ __forceinline__ float bf2f(unsigned short u) {
    union { unsigned short u; __hip_bfloat16 h; } cv; cv.u = u;
    return __bfloat162float(cv.h);
}
__device__ __forceinline__ unsigned int packsplit(float f) {
    unsigned short h = f2bf(f);
    unsigned short l = f2bf(f - bf2f(h));
    return (unsigned int)h | ((unsigned int)l << 16);
}
// unpack 8 consecutive packed u32 -> hi frag + lo frag (8 v_perm)
__device__ __forceinline__ void unpack_frag(const unsigned int* p8,
                                            s16x8* ah, s16x8* al) {
    uint4 a = *(const uint4*)p8;
    uint4 b = *(const uint4*)(p8 + 4);
    union { s16x8 v; unsigned int d[4]; } H, L;
    H.d[0] = __builtin_amdgcn_perm(a.y, a.x, 0x05040100u);
    H.d[1] = __builtin_amdgcn_perm(a.w, a.z, 0x05040100u);
    H.d[2] = __builtin_amdgcn_perm(b.y, b.x, 0x05040100u);
    H.d[3] = __builtin_amdgcn_perm(b.w, b.z, 0x05040100u);
    L.d[0] = __builtin_amdgcn_perm(a.y, a.x, 0x07060302u);
    L.d[1] = __builtin_amdgcn_perm(a.w, a.z, 0x07060302u);
    L.d[2] = __builtin_amdgcn_perm(b.y, b.x, 0x07060302u);
    L.d[3] = __builtin_amdgcn_perm(b.w, b.z, 0x07060302u);
    *ah = H.v; *al = L.v;
}

// swizzled [c][s] plane (64x64 shorts): 16B blocks XORed -> aligned b128 frags
__device__ __forceinline__ int swz(int c, int s) {
    return c * 64 + ((((s >> 3) ^ (c & 7)) << 3) | (s & 7));
}
// swizzled [s][c] plane
__device__ __forceinline__ int swz2(int s, int c) {
    return s * 64 + ((((c >> 3) ^ (s & 7)) << 3) | (c & 7));
}

// ---------------------------------------------------------------------------
// precompute A (blocks 0..255) and M (blocks 256..283), split-bf16 planes.
// ---------------------------------------------------------------------------
__global__ __launch_bounds__(256) void precompute_kernel(
    unsigned short* __restrict__ Ahi, unsigned short* __restrict__ Alo,
    unsigned short* __restrict__ MThi, unsigned short* __restrict__ MTlo)
{
    __shared__ float A[4][1024];
    __shared__ float Bf[4][520];
    __shared__ float hib[14];
    const int t = threadIdx.x;

    if (blockIdx.x < 256) {
        const int l = t & 63;
        const int g = t >> 6;
        const int s0 = blockIdx.x * 4 + g;

        for (int i = l; i < SLEN; i += 64) A[g][i] = (i == s0) ? 1.0f : 0.0f;
        __syncthreads();

        const int NIN[8]  = {1024, 517, 264, 137, 74, 42, 26, 18};
        const int NOUT[8] = { 517, 264, 137,  74, 42, 26, 18, 14};

#pragma unroll
        for (int lev = 0; lev < 8; ++lev) {
            float* in  = (lev & 1) ? Bf[g] : A[g];
            float* out = (lev & 1) ? A[g] : Bf[g];
            const int nin = NIN[lev], nout = NOUT[lev];
            for (int m = l; m < nout; m += 64) {
                float alo = 0.f, ahi = 0.f;
#pragma unroll
                for (int tt = 0; tt < 12; ++tt) {
                    int jj = 2 * m + tt - 10;
                    if (jj < 0)         jj = -1 - jj;
                    else if (jj >= nin) jj = 2 * nin - 1 - jj;
                    float xv = in[jj];
                    alo += xv * RLv[tt];
                    if (lev == 7) ahi += xv * AHv[tt];
                }
                out[m] = alo;
                if (lev == 7) {
                    unsigned short h1 = f2bf(alo);
                    Ahi[m * SLEN + s0] = h1;
                    Alo[m * SLEN + s0] = f2bf(alo - bf2f(h1));
                    unsigned short h2 = f2bf(ahi);
                    Ahi[(14 + m) * SLEN + s0] = h2;
                    Alo[(14 + m) * SLEN + s0] = f2bf(ahi - bf2f(h2));
                }
            }
            __syncthreads();
        }
        if (l < 4) {
            Ahi[(28 + l) * SLEN + s0] = 0; Alo[(28 + l) * SLEN + s0] = 0;
            MThi[s0 * 32 + 28 + l] = 0;    MTlo[s0 * 32 + 28 + l] = 0;
        }
        return;
    }

    const int u = blockIdx.x - 256;     // 0..27
    float* Af = A[0];
    float* Bff = Bf[0];
    if (t < 14) {
        Af[t]  = (u < 14 && t == u) ? 1.0f : 0.0f;
        hib[t] = (u >= 14 && t == (u - 14)) ? 1.0f : 0.0f;
    }
    __syncthreads();

    const int NH[8] = {14, 18, 26, 42, 74, 137, 264, 517};
    const int NO[8] = {18, 26, 42, 74, 138, 264, 518, 1024};

#pragma unroll
    for (int s = 0; s < 8; ++s) {
        const float* lo = (s & 1) ? Bff : Af;
        float* out      = (s & 1) ? Af : Bff;
        const int N = NH[s], nout = NO[s];
        for (int m = t; m < nout; m += 256) {
            float acc = 0.f;
#pragma unroll
            for (int tt = 0; tt < 12; ++tt) {
                int uu = m + tt - 1;
                if ((uu & 1) == 0) {
                    int q = uu >> 1;
                    if (q < N) {
                        acc += lo[q] * SLv[tt];
                        if (s == 0) acc += hib[q] * SHv[tt];
                    }
                }
            }
            out[m] = acc;
        }
        __syncthreads();
    }
    for (int m = t; m < SLEN; m += 256) {
        float f = Af[m];
        unsigned short h = f2bf(f);
        MThi[m * 32 + u] = h;
        MTlo[m * 32 + u] = f2bf(f - bf2f(h));
    }
}

// ---------------------------------------------------------------------------
// proj-MFMA body for barrier-style 64-s blocks (fc0proj only, 256 threads).
// ---------------------------------------------------------------------------
__device__ __forceinline__ void proj_mfma(
    const unsigned short* Phi, const unsigned short* Plo,
    const unsigned short* __restrict__ Ahi, const unsigned short* __restrict__ Alo,
    float* __restrict__ Ppart, int bb, int tile, int s0, int t)
{
    const int lane = t & 63;
    const int w    = t >> 6;
    const int qr   = lane >> 4;
    const int ln   = lane & 15;
    const int mt   = w >> 1;
    const int nb   = (w & 1) * 2;

    f32x4 acc[2];
    acc[0] = (f32x4){0.f,0.f,0.f,0.f};
    acc[1] = (f32x4){0.f,0.f,0.f,0.f};

#pragma unroll
    for (int kk = 0; kk < 2; ++kk) {
        const int k0 = kk * 32;
        const int arow = (mt * 16 + ln) * SLEN + s0 + k0 + qr * 8;
        s16x8 ah = *(const s16x8*)&Ahi[arow];
        s16x8 al = *(const s16x8*)&Alo[arow];
        const int bk = (k0 >> 3) + qr;
#pragma unroll
        for (int ni = 0; ni < 2; ++ni) {
            const int c = (nb + ni) * 16 + ln;
            const int boff = c * 64 + (((bk ^ (c & 7)) << 3));
            s16x8 bh = *(const s16x8*)&Phi[boff];
            s16x8 bl = *(const s16x8*)&Plo[boff];
            acc[ni] = __builtin_amdgcn_mfma_f32_16x16x32_bf16(ah, bh, acc[ni], 0, 0, 0);
            acc[ni] = __builtin_amdgcn_mfma_f32_16x16x32_bf16(al, bh, acc[ni], 0, 0, 0);
            acc[ni] = __builtin_amdgcn_mfma_f32_16x16x32_bf16(ah, bl, acc[ni], 0, 0, 0);
        }
    }
#pragma unroll
    for (int ni = 0; ni < 2; ++ni) {
#pragma unroll
        for (int r = 0; r < 4; ++r) {
            int xr = mt * 16 + qr * 4 + r;
            if (xr < 28) {
                int c = (nb + ni) * 16 + ln;
                Ppart[((size_t)(bb * NT + tile) * 28 + xr) * 64 + c] = acc[ni][r];
            }
        }
    }
}

// ---------------------------------------------------------------------------
// fc0 + proj0 + prep, one dispatch. v output is packed u32.
// ---------------------------------------------------------------------------
__global__ __launch_bounds__(256, 4) void fc0proj_kernel(
    const float* __restrict__ x,
    const float* __restrict__ fc0w_0, const float* __restrict__ fc0b_0,
    const float* __restrict__ fc0w_1, const float* __restrict__ fc0b_1,
    const float* __restrict__ fc1w_0, const float* __restrict__ fc1w_1,
    const unsigned short* __restrict__ Ahi, const unsigned short* __restrict__ Alo,
    unsigned int* __restrict__ v0, unsigned int* __restrict__ v1,
    unsigned short* __restrict__ w1hi, unsigned short* __restrict__ w1lo,
    unsigned short* __restrict__ Dhi,  unsigned short* __restrict__ Dlo,
    float* __restrict__ Ppart)
{
    const int t = threadIdx.x;
    if (blockIdx.x >= 2048) {
        const int gid = (blockIdx.x - 2048) * 256 + t;
        for (int idx = gid; idx < 16384; idx += 2048) {
            int br = idx >> 13, r = idx & 8191;
            int h = r >> 6, c = r & 63;
            float f = (br ? fc1w_1 : fc1w_0)[c * 128 + h];
            unsigned short hh = f2bf(f);
            w1hi[idx] = hh;
            w1lo[idx] = f2bf(f - bf2f(hh));
        }
        for (int idx = gid; idx < 32768; idx += 2048) {
            int bb = idx >> 8, o = (idx >> 2) & 63, j = idx & 3;
            Dhi[bb * 2048 + o * 32 + 28 + j] = 0;
            Dlo[bb * 2048 + o * 32 + 28 + j] = 0;
        }
        return;
    }

    __shared__ unsigned short Phi[4096];
    __shared__ unsigned short Plo[4096];
    const int bb   = blockIdx.x >> 4;
    const int tile = blockIdx.x & 15;
    const int br = bb >> 6, b = bb & 63;
    const int s0 = tile << 6;
    const float* fc0w = br ? fc0w_1 : fc0w_0;
    const float* fc0b = br ? fc0b_1 : fc0b_0;
    unsigned int* vpk = br ? v1 : v0;
    const size_t base = ((size_t)b * SLEN + s0) * 64;

    for (int idx = t; idx < 4096; idx += 256) {
        int s = idx >> 6, c = idx & 63;
        float val = x[b * SLEN + s0 + s] * fc0w[c]
                  + (float)(s0 + s) * (1.0f / 1023.0f) * fc0w[WCH + c] + fc0b[c];
        unsigned short h = f2bf(val);
        unsigned short l = f2bf(val - bf2f(h));
        vpk[base + idx] = (unsigned int)h | ((unsigned int)l << 16);
        int a = swz(c, s);
        Phi[a] = h;
        Plo[a] = l;
    }
    __syncthreads();
    proj_mfma(Phi, Plo, Ahi, Alo, Ppart, bb, tile, s0, t);
}

// ---------------------------------------------------------------------------
// Mix (per layer) — unchanged.
// ---------------------------------------------------------------------------
__global__ __launch_bounds__(256) void mix_kernel(
    const float* __restrict__ Ppart,
    const float* __restrict__ w1_0, const float* __restrict__ w2_0,
    const float* __restrict__ w1_1, const float* __restrict__ w2_1,
    const float* __restrict__ cw_0, const float* __restrict__ cw_1,
    unsigned short* __restrict__ cwPhi, unsigned short* __restrict__ cwPlo,
    unsigned short* __restrict__ Dhi, unsigned short* __restrict__ Dlo)
{
    const int t = threadIdx.x;
    const int br  = blockIdx.x / 225;
    const int sub = blockIdx.x % 225;

    if (sub == 224) {
        const float* cw = br ? cw_1 : cw_0;
        for (int idx = t; idx < 4096; idx += 256) {
            int k = idx >> 6, o = idx & 63;
            float val = cw[o * 64 + k] + ((k == o) ? 1.0f : 0.0f);
            unsigned short h = f2bf(val);
            cwPhi[br * 4096 + o * 64 + k] = h;
            cwPlo[br * 4096 + o * 64 + k] = f2bf(val - bf2f(h));
        }
        return;
    }

    __shared__ float Ws[64][65];
    __shared__ float LO[8][64];
    const int o = t & 63;
    const int w = t >> 6;
    const int x  = sub >> 3;
    const int b0 = (sub & 7) << 3;

    const float* wbase = (x < 14) ? (br ? w1_1 : w1_0) : (br ? w2_1 : w2_0);
    const int xi = (x < 14) ? x : (x - 14);
    for (int idx = t; idx < 4096; idx += 256)
        Ws[idx >> 6][idx & 63] = wbase[(size_t)idx * 14 + xi];

#pragma unroll
    for (int j = 0; j < 2; ++j) {
        int bi = w + 4 * j;
        int bb = br * 64 + b0 + bi;
        float s = 0.f;
        for (int tile = 0; tile < NT; ++tile)
            s += Ppart[((size_t)(bb * NT + tile) * 28 + x) * 64 + o];
        LO[bi][o] = s;
    }
    __syncthreads();

#pragma unroll
    for (int j = 0; j < 2; ++j) {
        int bi = w + 4 * j;
        int bb = br * 64 + b0 + bi;
        float acc = 0.f;
        for (int i = 0; i < 64; ++i)
            acc += LO[bi][i] * Ws[i][o];
        acc -= LO[bi][o];
        unsigned short h = f2bf(acc);
        Dhi[bb * 2048 + o * 32 + x] = h;
        Dlo[bb * 2048 + o * 32 + x] = f2bf(acc - bf2f(h));
    }
}

// ---------------------------------------------------------------------------
// Fused layer (i = 0,1,2): 128-thread blocks, 2 waves per 64-s tile, each wave
// owns a 32-o half. B frags register-resident; packed v in/out; proj reads
// only own wave's c-half -> NO barriers. grid 2048.
// ---------------------------------------------------------------------------
__global__ __launch_bounds__(128, 3) void layer_kernel(
    const unsigned int* __restrict__ vin0, const unsigned int* __restrict__ vin1,
    unsigned int* __restrict__ vout0, unsigned int* __restrict__ vout1,
    const unsigned short* __restrict__ MThi, const unsigned short* __restrict__ MTlo,
    const unsigned short* __restrict__ Ahi,  const unsigned short* __restrict__ Alo,
    const unsigned short* __restrict__ cwPhi, const unsigned short* __restrict__ cwPlo,
    const unsigned short* __restrict__ Dhi,   const unsigned short* __restrict__ Dlo,
    const float* __restrict__ cb_0, const float* __restrict__ cb_1,
    float* __restrict__ Ppart)
{
    __shared__ unsigned short Phi[4096];   // block-shared swizzled [c][s64]
    __shared__ unsigned short Plo[4096];

    const int t = threadIdx.x;
    const int bid = blockIdx.x;
    const int br  = bid >> 10;
    const int rem = bid & 1023;
    const int b    = rem >> 4;
    const int tile = rem & 15;
    const int s0   = tile << 6;
    const size_t bS = (size_t)b * SLEN;
    const unsigned int* vin = br ? vin1 : vin0;
    unsigned int* vout      = br ? vout1 : vout0;
    const float* cb = br ? cb_1 : cb_0;
    const int bb = br * 64 + b;

    const int lane = t & 63;
    const int w    = t >> 6;          // 0..1: o-half
    const int qr   = lane >> 4;
    const int ln   = lane & 15;

    // ---- preload B fragments for this wave's o-half ----
    s16x8 Bh[2][2], Bl[2][2];
#pragma unroll
    for (int kk = 0; kk < 2; ++kk)
#pragma unroll
        for (int ni = 0; ni < 2; ++ni) {
            const int o = w * 32 + ni * 16 + ln;
            const int boff = br * 4096 + o * 64 + kk * 32 + qr * 8;
            Bh[kk][ni] = *(const s16x8*)&cwPhi[boff];
            Bl[kk][ni] = *(const s16x8*)&cwPlo[boff];
        }
    s16x8 Dhf[2], Dlf[2];
#pragma unroll
    for (int ni = 0; ni < 2; ++ni) {
        const int o = w * 32 + ni * 16 + ln;
        const int boff = bb * 2048 + o * 32 + qr * 8;
        Dhf[ni] = *(const s16x8*)&Dhi[boff];
        Dlf[ni] = *(const s16x8*)&Dlo[boff];
    }
    float cbv[2];
#pragma unroll
    for (int ni = 0; ni < 2; ++ni) cbv[ni] = cb[w * 32 + ni * 16 + ln];

    // ---- 4 m-tiles ----
#pragma unroll
    for (int mi = 0; mi < 4; ++mi) {
        const int srow = mi * 16 + ln;
        f32x4 acc[2];
        acc[0] = (f32x4){0.f,0.f,0.f,0.f};
        acc[1] = (f32x4){0.f,0.f,0.f,0.f};

#pragma unroll
        for (int kk = 0; kk < 2; ++kk) {
            const size_t aoff = (bS + s0 + srow) * 64 + kk * 32 + qr * 8;
            s16x8 ah, al;
            unpack_frag(&vin[aoff], &ah, &al);
#pragma unroll
            for (int ni = 0; ni < 2; ++ni) {
                acc[ni] = __builtin_amdgcn_mfma_f32_16x16x32_bf16(ah, Bh[kk][ni], acc[ni], 0, 0, 0);
                acc[ni] = __builtin_amdgcn_mfma_f32_16x16x32_bf16(al, Bh[kk][ni], acc[ni], 0, 0, 0);
                acc[ni] = __builtin_amdgcn_mfma_f32_16x16x32_bf16(ah, Bl[kk][ni], acc[ni], 0, 0, 0);
            }
        }
        {
            const size_t aoff = (size_t)(s0 + srow) * 32 + qr * 8;
            s16x8 ah = *(const s16x8*)&MThi[aoff];
            s16x8 al = *(const s16x8*)&MTlo[aoff];
#pragma unroll
            for (int ni = 0; ni < 2; ++ni) {
                acc[ni] = __builtin_amdgcn_mfma_f32_16x16x32_bf16(ah, Dhf[ni], acc[ni], 0, 0, 0);
                acc[ni] = __builtin_amdgcn_mfma_f32_16x16x32_bf16(al, Dhf[ni], acc[ni], 0, 0, 0);
                acc[ni] = __builtin_amdgcn_mfma_f32_16x16x32_bf16(ah, Dlf[ni], acc[ni], 0, 0, 0);
            }
        }
        // epilogue: gelu, split, packed global store + LDS (own c-half)
#pragma unroll
        for (int ni = 0; ni < 2; ++ni) {
            const int o = w * 32 + ni * 16 + ln;
#pragma unroll
            for (int r = 0; r < 4; ++r) {
                const int sl64 = mi * 16 + qr * 4 + r;
                float val = gelu_f(acc[ni][r] + cbv[ni]);
                unsigned short h = f2bf(val);
                unsigned short l = f2bf(val - bf2f(h));
                vout[(bS + s0 + sl64) * 64 + o] =
                    (unsigned int)h | ((unsigned int)l << 16);
                const int a = swz(o, sl64);
                Phi[a] = h;
                Plo[a] = l;
            }
        }
    }

    // ---- proj on own c-half (same-wave LDS RAW: no barrier needed) ----
    f32x4 pacc[2][2];
#pragma unroll
    for (int mt = 0; mt < 2; ++mt)
#pragma unroll
        for (int ni = 0; ni < 2; ++ni) pacc[mt][ni] = (f32x4){0.f,0.f,0.f,0.f};

#pragma unroll
    for (int kk = 0; kk < 2; ++kk) {
        const int bk = kk * 4 + qr;
        s16x8 pah[2], pal[2];
#pragma unroll
        for (int mt = 0; mt < 2; ++mt) {
            const int arow = (mt * 16 + ln) * SLEN + s0 + kk * 32 + qr * 8;
            pah[mt] = *(const s16x8*)&Ahi[arow];
            pal[mt] = *(const s16x8*)&Alo[arow];
        }
#pragma unroll
        for (int ni = 0; ni < 2; ++ni) {
            const int c = w * 32 + ni * 16 + ln;
            const int boff = c * 64 + ((bk ^ (c & 7)) << 3);
            s16x8 bh = *(const s16x8*)&Phi[boff];
            s16x8 bl = *(const s16x8*)&Plo[boff];
#pragma unroll
            for (int mt = 0; mt < 2; ++mt) {
                pacc[mt][ni] = __builtin_amdgcn_mfma_f32_16x16x32_bf16(pah[mt], bh, pacc[mt][ni], 0, 0, 0);
                pacc[mt][ni] = __builtin_amdgcn_mfma_f32_16x16x32_bf16(pal[mt], bh, pacc[mt][ni], 0, 0, 0);
                pacc[mt][ni] = __builtin_amdgcn_mfma_f32_16x16x32_bf16(pah[mt], bl, pacc[mt][ni], 0, 0, 0);
            }
        }
    }
#pragma unroll
    for (int mt = 0; mt < 2; ++mt)
#pragma unroll
        for (int ni = 0; ni < 2; ++ni) {
            const int c = w * 32 + ni * 16 + ln;
#pragma unroll
            for (int r = 0; r < 4; ++r) {
                const int xr = mt * 16 + qr * 4 + r;
                if (xr < 28)
                    Ppart[((size_t)(bb * NT + tile) * 28 + xr) * 64 + c] = pacc[mt][ni][r];
            }
        }
}

// ---------------------------------------------------------------------------
// Head with fused layer 3: 128-thread blocks (2 waves per 64-s tile).
// Packed v input. Phase A per-wave 32-o half -> shared LDS, one barrier.
// Phase B: 64-h half of fc1, gelu*fc2, shfl-reduce, atomicAdd into out.
// ---------------------------------------------------------------------------
__global__ __launch_bounds__(128, 3) void head_kernel(
    const unsigned int* __restrict__ vin0, const unsigned int* __restrict__ vin1,
    const unsigned short* __restrict__ MThi, const unsigned short* __restrict__ MTlo,
    const unsigned short* __restrict__ cwPhi, const unsigned short* __restrict__ cwPlo,
    const unsigned short* __restrict__ Dhi,   const unsigned short* __restrict__ Dlo,
    const float* __restrict__ cb_0, const float* __restrict__ cb_1,
    const unsigned short* __restrict__ w1hi, const unsigned short* __restrict__ w1lo,
    const float* __restrict__ fc1b_0, const float* __restrict__ fc2w_0,
    const float* __restrict__ fc2b_0,
    const float* __restrict__ fc1b_1, const float* __restrict__ fc2w_1,
    const float* __restrict__ fc2b_1,
    float* __restrict__ out)
{
    __shared__ unsigned short Vh[4096];    // block-shared swz2 [s64][c]
    __shared__ unsigned short Vl[4096];

    const int t = threadIdx.x;
    const int bid = blockIdx.x;
    const int br  = bid >> 10;
    const int rem = bid & 1023;
    const int b    = rem >> 4;
    const int tile = rem & 15;
    const int s0   = tile << 6;
    const size_t bS = (size_t)b * SLEN;

    const int lane = t & 63;
    const int w    = t >> 6;          // 0..1
    const int qr   = lane >> 4;
    const int ln   = lane & 15;

    const unsigned int* vin = br ? vin1 : vin0;
    const float* cb   = br ? cb_1 : cb_0;
    const float* fc1b = br ? fc1b_1 : fc1b_0;
    const float* fc2w = br ? fc2w_1 : fc2w_0;
    const float fc2b  = (br ? fc2b_1 : fc2b_0)[0];
    const int bb = br * 64 + b;

    // ---- phase A: layer-3, own 32-o half ----
    {
        s16x8 Bh[2][2], Bl[2][2];
#pragma unroll
        for (int kk = 0; kk < 2; ++kk)
#pragma unroll
            for (int ni = 0; ni < 2; ++ni) {
                const int o = w * 32 + ni * 16 + ln;
                const int boff = br * 4096 + o * 64 + kk * 32 + qr * 8;
                Bh[kk][ni] = *(const s16x8*)&cwPhi[boff];
                Bl[kk][ni] = *(const s16x8*)&cwPlo[boff];
            }
        s16x8 Dhf[2], Dlf[2];
#pragma unroll
        for (int ni = 0; ni < 2; ++ni) {
            const int o = w * 32 + ni * 16 + ln;
            const int boff = bb * 2048 + o * 32 + qr * 8;
            Dhf[ni] = *(const s16x8*)&Dhi[boff];
            Dlf[ni] = *(const s16x8*)&Dlo[boff];
        }
        float cbv[2];
#pragma unroll
        for (int ni = 0; ni < 2; ++ni) cbv[ni] = cb[w * 32 + ni * 16 + ln];

#pragma unroll
        for (int mi = 0; mi < 4; ++mi) {
            const int srow = mi * 16 + ln;
            f32x4 acc[2];
            acc[0] = (f32x4){0.f,0.f,0.f,0.f};
            acc[1] = (f32x4){0.f,0.f,0.f,0.f};

#pragma unroll
            for (int kk = 0; kk < 2; ++kk) {
                const size_t aoff = (bS + s0 + srow) * 64 + kk * 32 + qr * 8;
                s16x8 ah, al;
                unpack_frag(&vin[aoff], &ah, &al);
#pragma unroll
                for (int ni = 0; ni < 2; ++ni) {
                    acc[ni] = __builtin_amdgcn_mfma_f32_16x16x32_bf16(ah, Bh[kk][ni], acc[ni], 0, 0, 0);
                    acc[ni] = __builtin_amdgcn_mfma_f32_16x16x32_bf16(al, Bh[kk][ni], acc[ni], 0, 0, 0);
                    acc[ni] = __builtin_amdgcn_mfma_f32_16x16x32_bf16(ah, Bl[kk][ni], acc[ni], 0, 0, 0);
                }
            }
            {
                const size_t aoff = (size_t)(s0 + srow) * 32 + qr * 8;
                s16x8 ah = *(const s16x8*)&MThi[aoff];
                s16x8 al = *(const s16x8*)&MTlo[aoff];
#pragma unroll
                for (int ni = 0; ni < 2; ++ni) {
                    acc[ni] = __builtin_amdgcn_mfma_f32_16x16x32_bf16(ah, Dhf[ni], acc[ni], 0, 0, 0);
                    acc[ni] = __builtin_amdgcn_mfma_f32_16x16x32_bf16(al, Dhf[ni], acc[ni], 0, 0, 0);
                    acc[ni] = __builtin_amdgcn_mfma_f32_16x16x32_bf16(ah, Dlf[ni], acc[ni], 0, 0, 0);
                }
            }
#pragma unroll
            for (int ni = 0; ni < 2; ++ni) {
                const int o = w * 32 + ni * 16 + ln;
#pragma unroll
                for (int r = 0; r < 4; ++r) {
                    const int sl64 = mi * 16 + qr * 4 + r;
                    float val = acc[ni][r] + cbv[ni];
                    unsigned short h = f2bf(val);
                    unsigned short l = f2bf(val - bf2f(h));
                    const int a = swz2(sl64, o);
                    Vh[a] = h;
                    Vl[a] = l;
                }
            }
        }
    }
    __syncthreads();

    // ---- phase B: fc1 GEMM, own 64-h half ----
    s16x8 Wh[2][4], Wl[2][4];
#pragma unroll
    for (int kk = 0; kk < 2; ++kk)
#pragma unroll
        for (int ni = 0; ni < 4; ++ni) {
            const int h = w * 64 + ni * 16 + ln;
            const int boff = br * 8192 + h * 64 + kk * 32 + qr * 8;
            Wh[kk][ni] = *(const s16x8*)&w1hi[boff];
            Wl[kk][ni] = *(const s16x8*)&w1lo[boff];
        }
    float b1v[4], w2v[4];
#pragma unroll
    for (int ni = 0; ni < 4; ++ni) {
        b1v[ni] = fc1b[w * 64 + ni * 16 + ln];
        w2v[ni] = fc2w[w * 64 + ni * 16 + ln];
    }

#pragma unroll
    for (int mi = 0; mi < 4; ++mi) {
        f32x4 acc1[4];
#pragma unroll
        for (int ni = 0; ni < 4; ++ni) acc1[ni] = (f32x4){0.f,0.f,0.f,0.f};

#pragma unroll
        for (int kk = 0; kk < 2; ++kk) {
            const int blk = kk * 4 + qr;
            const int sl  = mi * 16 + ln;
            const int a   = sl * 64 + ((blk ^ (sl & 7)) << 3);
            s16x8 ah = *(const s16x8*)&Vh[a];
            s16x8 al = *(const s16x8*)&Vl[a];
#pragma unroll
            for (int ni = 0; ni < 4; ++ni) {
                acc1[ni] = __builtin_amdgcn_mfma_f32_16x16x32_bf16(ah, Wh[kk][ni], acc1[ni], 0, 0, 0);
                acc1[ni] = __builtin_amdgcn_mfma_f32_16x16x32_bf16(al, Wh[kk][ni], acc1[ni], 0, 0, 0);
                acc1[ni] = __builtin_amdgcn_mfma_f32_16x16x32_bf16(ah, Wl[kk][ni], acc1[ni], 0, 0, 0);
            }
        }
        float partial[4] = {0.f, 0.f, 0.f, 0.f};
#pragma unroll
        for (int ni = 0; ni < 4; ++ni) {
#pragma unroll
            for (int r = 0; r < 4; ++r)
                partial[r] += gelu_f(acc1[ni][r] + b1v[ni]) * w2v[ni];
        }
#pragma unroll
        for (int r = 0; r < 4; ++r) {
            partial[r] += __shfl_xor(partial[r], 1, 64);
            partial[r] += __shfl_xor(partial[r], 2, 64);
            partial[r] += __shfl_xor(partial[r], 4, 64);
            partial[r] += __shfl_xor(partial[r], 8, 64);
        }
        if (ln == 0) {
            const float bias = (w == 0) ? fc2b : 0.f;
#pragma unroll
            for (int r = 0; r < 4; ++r)
                atomicAdd(&out[bS + s0 + mi * 16 + qr * 4 + r],
                          partial[r] + bias);
        }
    }
}

// ---------------------------------------------------------------------------
extern "C" void kernel_launch(void* const* d_in, const int* in_sizes, int n_in,
                              void* d_out, int out_size, void* d_ws, size_t ws_size,
                              hipStream_t stream)
{
    const float* x = (const float*)d_in[0];
    const float* P[2][10];
    for (int br = 0; br < 2; ++br)
        for (int k = 0; k < 10; ++k)
            P[br][k] = (const float*)d_in[1 + br * 10 + k];
    // order: fc0_w, fc0_b, wave_w1, wave_w2, cw, cb, fc1_w, fc1_b, fc2_w, fc2_b

    char* p = (char*)d_ws;
    const size_t PL = (size_t)BC * SLEN * 4;   // one packed u32 plane: 16.78 MB
    unsigned int* vplane[4];                   // [br][pingpong]
    for (int i = 0; i < 4; ++i) { vplane[i] = (unsigned int*)p; p += PL; }
    unsigned short* Ahi  = (unsigned short*)p; p += 32 * SLEN * 2;
    unsigned short* Alo  = (unsigned short*)p; p += 32 * SLEN * 2;
    unsigned short* MThi = (unsigned short*)p; p += SLEN * 32 * 2;
    unsigned short* MTlo = (unsigned short*)p; p += SLEN * 32 * 2;
    float* Ppart = (float*)p;                  p += (size_t)128 * NT * 28 * 64 * 4;
    unsigned short* cwPhi = (unsigned short*)p; p += 2 * 4096 * 2;
    unsigned short* cwPlo = (unsigned short*)p; p += 2 * 4096 * 2;
    unsigned short* Dhi   = (unsigned short*)p; p += (size_t)128 * 2048 * 2;
    unsigned short* Dlo   = (unsigned short*)p; p += (size_t)128 * 2048 * 2;
    unsigned short* w1hi  = (unsigned short*)p; p += 2 * 8192 * 2;
    unsigned short* w1lo  = (unsigned short*)p; p += 2 * 8192 * 2;

    unsigned int *v0a = vplane[0], *v0b = vplane[1];
    unsigned int *v1a = vplane[2], *v1b = vplane[3];

    precompute_kernel<<<284, 256, 0, stream>>>(Ahi, Alo, MThi, MTlo);

    hipMemsetAsync(d_out, 0, (size_t)out_size * sizeof(float), stream);

    fc0proj_kernel<<<2056, 256, 0, stream>>>(
        x, P[0][0], P[0][1], P[1][0], P[1][1], P[0][6], P[1][6],
        Ahi, Alo, v0a, v1a, w1hi, w1lo, Dhi, Dlo, Ppart);

    for (int i = 0; i < 3; ++i) {
        mix_kernel<<<450, 256, 0, stream>>>(
            Ppart,
            P[0][2] + (size_t)i * WCH * WCH * 14, P[0][3] + (size_t)i * WCH * WCH * 14,
            P[1][2] + (size_t)i * WCH * WCH * 14, P[1][3] + (size_t)i * WCH * WCH * 14,
            P[0][4] + (size_t)i * WCH * WCH,      P[1][4] + (size_t)i * WCH * WCH,
            cwPhi, cwPlo, Dhi, Dlo);
        layer_kernel<<<2048, 128, 0, stream>>>(
            v0a, v1a, v0b, v1b,
            MThi, MTlo, Ahi, Alo, cwPhi, cwPlo, Dhi, Dlo,
            P[0][5] + (size_t)i * WCH, P[1][5] + (size_t)i * WCH,
            Ppart);
        unsigned int* tmp;
        tmp = v0a; v0a = v0b; v0b = tmp;
        tmp = v1a; v1a = v1b; v1b = tmp;
    }

    mix_kernel<<<450, 256, 0, stream>>>(
        Ppart,
        P[0][2] + (size_t)3 * WCH * WCH * 14, P[0][3] + (size_t)3 * WCH * WCH * 14,
        P[1][2] + (size_t)3 * WCH * WCH * 14, P[1][3] + (size_t)3 * WCH * WCH * 14,
        P[0][4] + (size_t)3 * WCH * WCH,      P[1][4] + (size_t)3 * WCH * WCH,
        cwPhi, cwPlo, Dhi, Dlo);

    head_kernel<<<2048, 128, 0, stream>>>(
        v0a, v1a,
        MThi, MTlo, cwPhi, cwPlo, Dhi, Dlo,
        P[0][5] + (size_t)3 * WCH, P[1][5] + (size_t)3 * WCH,
        w1hi, w1lo,
        P[0][7], P[0][8], P[0][9],
        P[1][7], P[1][8], P[1][9],
        (float*)d_out);
}

// Round 17
// 284.446 us; speedup vs baseline: 1.0437x; 1.0100x over previous
//
#include <hip/hip_runtime.h>
#include <hip/hip_bf16.h>
#include <math.h>

// ---------------------------------------------------------------------------
// WNO1d. wave_conv(v) = v + Syn(W1*lo8-lo8, W2*hi8-hi8)  (perfect reconstruction;
// intermediate highs pass through). Constant operators, computed on device:
//   A  (28x1024 analysis)  -> split-bf16 planes Ahi/Alo [32][1024] (pad rows 0)
//   M^T(28x1024 synthesis) -> split-bf16 planes MThi/MTlo [1024][32] (pad 0)
// Activations: PACKED split-bf16 planes v[b][s][c] as u32 = hi | lo<<16
// (one dword store per value, consumers unpack with v_perm). All GEMMs on MFMA
// (split-bf16 3-mfma = fp32-grade).
// Round 17: revert to proven round-15 kernel (287 µs). Round 16's cooperative
// mega-kernel raced under graph capture (grid.sync not honored) — reverted.
// ---------------------------------------------------------------------------

#define BDIM 64
#define SLEN 1024
#define WCH  64
#define BC   (BDIM*WCH)
#define NT   16         // 64-s proj tiles per batch

typedef short s16x8 __attribute__((ext_vector_type(8)));
typedef float f32x4 __attribute__((ext_vector_type(4)));

constexpr float RLv[12] = {
    0.11154074335008017f, 0.4946238903983854f, 0.7511339080215775f,
    0.3152503517092432f, -0.22626469396516913f, -0.12976686756709563f,
    0.09750160558707936f, 0.02752286553001629f, -0.031582039318031156f,
    0.0005538422009938016f, 0.004777257511010651f, -0.00107730108499558f };
constexpr float AHv[12] = {
     RLv[11], -RLv[10],  RLv[9], -RLv[8],  RLv[7], -RLv[6],
     RLv[5],  -RLv[4],   RLv[3], -RLv[2],  RLv[1], -RLv[0] };
constexpr float SLv[12] = {
     RLv[11], RLv[10], RLv[9], RLv[8], RLv[7], RLv[6],
     RLv[5],  RLv[4],  RLv[3], RLv[2], RLv[1], RLv[0] };
constexpr float SHv[12] = {
    -RLv[0],  RLv[1], -RLv[2],  RLv[3], -RLv[4],  RLv[5],
    -RLv[6],  RLv[7], -RLv[8],  RLv[9], -RLv[10], RLv[11] };

// fast gelu: x * sigmoid(2*0.79788*(x+0.044715x^3)); <=~4e-4 dev/application.
__device__ __forceinline__ float gelu_f(float x) {
    float z = 0.7978845608f * (x + 0.044715f * x * x * x);
    return x / (1.0f + __expf(-2.0f * z));
}
__device__ __forceinline__ unsigned short f2bf(float f) {
    __hip_bfloat16 h = __float2bfloat16(f);
    union { __hip_bfloat16 h; unsigned short u; } cv; cv.h = h; return cv.u;
}
__device__ __forceinline__ float bf2f(unsigned short u) {
    union { unsigned short u; __hip_bfloat16 h; } cv; cv.u = u;
    return __bfloat162float(cv.h);
}
// unpack 8 consecutive packed u32 -> hi frag + lo frag (8 v_perm)
__device__ __forceinline__ void unpack_frag(const unsigned int* p8,
                                            s16x8* ah, s16x8* al) {
    uint4 a = *(const uint4*)p8;
    uint4 b = *(const uint4*)(p8 + 4);
    union { s16x8 v; unsigned int d[4]; } H, L;
    H.d[0] = __builtin_amdgcn_perm(a.y, a.x, 0x05040100u);
    H.d[1] = __builtin_amdgcn_perm(a.w, a.z, 0x05040100u);
    H.d[2] = __builtin_amdgcn_perm(b.y, b.x, 0x05040100u);
    H.d[3] = __builtin_amdgcn_perm(b.w, b.z, 0x05040100u);
    L.d[0] = __builtin_amdgcn_perm(a.y, a.x, 0x07060302u);
    L.d[1] = __builtin_amdgcn_perm(a.w, a.z, 0x07060302u);
    L.d[2] = __builtin_amdgcn_perm(b.y, b.x, 0x07060302u);
    L.d[3] = __builtin_amdgcn_perm(b.w, b.z, 0x07060302u);
    *ah = H.v; *al = L.v;
}

// swizzled [c][s] plane (64x64 shorts): 16B blocks XORed -> aligned b128 frags
__device__ __forceinline__ int swz(int c, int s) {
    return c * 64 + ((((s >> 3) ^ (c & 7)) << 3) | (s & 7));
}
// swizzled [s][c] plane
__device__ __forceinline__ int swz2(int s, int c) {
    return s * 64 + ((((c >> 3) ^ (s & 7)) << 3) | (c & 7));
}

// ---------------------------------------------------------------------------
// precompute A (blocks 0..255) and M (blocks 256..283), split-bf16 planes.
// ---------------------------------------------------------------------------
__global__ __launch_bounds__(256) void precompute_kernel(
    unsigned short* __restrict__ Ahi, unsigned short* __restrict__ Alo,
    unsigned short* __restrict__ MThi, unsigned short* __restrict__ MTlo)
{
    __shared__ float A[4][1024];
    __shared__ float Bf[4][520];
    __shared__ float hib[14];
    const int t = threadIdx.x;

    if (blockIdx.x < 256) {
        const int l = t & 63;
        const int g = t >> 6;
        const int s0 = blockIdx.x * 4 + g;

        for (int i = l; i < SLEN; i += 64) A[g][i] = (i == s0) ? 1.0f : 0.0f;
        __syncthreads();

        const int NIN[8]  = {1024, 517, 264, 137, 74, 42, 26, 18};
        const int NOUT[8] = { 517, 264, 137,  74, 42, 26, 18, 14};

#pragma unroll
        for (int lev = 0; lev < 8; ++lev) {
            float* in  = (lev & 1) ? Bf[g] : A[g];
            float* out = (lev & 1) ? A[g] : Bf[g];
            const int nin = NIN[lev], nout = NOUT[lev];
            for (int m = l; m < nout; m += 64) {
                float alo = 0.f, ahi = 0.f;
#pragma unroll
                for (int tt = 0; tt < 12; ++tt) {
                    int jj = 2 * m + tt - 10;
                    if (jj < 0)         jj = -1 - jj;
                    else if (jj >= nin) jj = 2 * nin - 1 - jj;
                    float xv = in[jj];
                    alo += xv * RLv[tt];
                    if (lev == 7) ahi += xv * AHv[tt];
                }
                out[m] = alo;
                if (lev == 7) {
                    unsigned short h1 = f2bf(alo);
                    Ahi[m * SLEN + s0] = h1;
                    Alo[m * SLEN + s0] = f2bf(alo - bf2f(h1));
                    unsigned short h2 = f2bf(ahi);
                    Ahi[(14 + m) * SLEN + s0] = h2;
                    Alo[(14 + m) * SLEN + s0] = f2bf(ahi - bf2f(h2));
                }
            }
            __syncthreads();
        }
        if (l < 4) {
            Ahi[(28 + l) * SLEN + s0] = 0; Alo[(28 + l) * SLEN + s0] = 0;
            MThi[s0 * 32 + 28 + l] = 0;    MTlo[s0 * 32 + 28 + l] = 0;
        }
        return;
    }

    const int u = blockIdx.x - 256;     // 0..27
    float* Af = A[0];
    float* Bff = Bf[0];
    if (t < 14) {
        Af[t]  = (u < 14 && t == u) ? 1.0f : 0.0f;
        hib[t] = (u >= 14 && t == (u - 14)) ? 1.0f : 0.0f;
    }
    __syncthreads();

    const int NH[8] = {14, 18, 26, 42, 74, 137, 264, 517};
    const int NO[8] = {18, 26, 42, 74, 138, 264, 518, 1024};

#pragma unroll
    for (int s = 0; s < 8; ++s) {
        const float* lo = (s & 1) ? Bff : Af;
        float* out      = (s & 1) ? Af : Bff;
        const int N = NH[s], nout = NO[s];
        for (int m = t; m < nout; m += 256) {
            float acc = 0.f;
#pragma unroll
            for (int tt = 0; tt < 12; ++tt) {
                int uu = m + tt - 1;
                if ((uu & 1) == 0) {
                    int q = uu >> 1;
                    if (q < N) {
                        acc += lo[q] * SLv[tt];
                        if (s == 0) acc += hib[q] * SHv[tt];
                    }
                }
            }
            out[m] = acc;
        }
        __syncthreads();
    }
    for (int m = t; m < SLEN; m += 256) {
        float f = Af[m];
        unsigned short h = f2bf(f);
        MThi[m * 32 + u] = h;
        MTlo[m * 32 + u] = f2bf(f - bf2f(h));
    }
}

// ---------------------------------------------------------------------------
// proj-MFMA body for barrier-style 64-s blocks (fc0proj only, 256 threads).
// ---------------------------------------------------------------------------
__device__ __forceinline__ void proj_mfma(
    const unsigned short* Phi, const unsigned short* Plo,
    const unsigned short* __restrict__ Ahi, const unsigned short* __restrict__ Alo,
    float* __restrict__ Ppart, int bb, int tile, int s0, int t)
{
    const int lane = t & 63;
    const int w    = t >> 6;
    const int qr   = lane >> 4;
    const int ln   = lane & 15;
    const int mt   = w >> 1;
    const int nb   = (w & 1) * 2;

    f32x4 acc[2];
    acc[0] = (f32x4){0.f,0.f,0.f,0.f};
    acc[1] = (f32x4){0.f,0.f,0.f,0.f};

#pragma unroll
    for (int kk = 0; kk < 2; ++kk) {
        const int k0 = kk * 32;
        const int arow = (mt * 16 + ln) * SLEN + s0 + k0 + qr * 8;
        s16x8 ah = *(const s16x8*)&Ahi[arow];
        s16x8 al = *(const s16x8*)&Alo[arow];
        const int bk = (k0 >> 3) + qr;
#pragma unroll
        for (int ni = 0; ni < 2; ++ni) {
            const int c = (nb + ni) * 16 + ln;
            const int boff = c * 64 + (((bk ^ (c & 7)) << 3));
            s16x8 bh = *(const s16x8*)&Phi[boff];
            s16x8 bl = *(const s16x8*)&Plo[boff];
            acc[ni] = __builtin_amdgcn_mfma_f32_16x16x32_bf16(ah, bh, acc[ni], 0, 0, 0);
            acc[ni] = __builtin_amdgcn_mfma_f32_16x16x32_bf16(al, bh, acc[ni], 0, 0, 0);
            acc[ni] = __builtin_amdgcn_mfma_f32_16x16x32_bf16(ah, bl, acc[ni], 0, 0, 0);
        }
    }
#pragma unroll
    for (int ni = 0; ni < 2; ++ni) {
#pragma unroll
        for (int r = 0; r < 4; ++r) {
            int xr = mt * 16 + qr * 4 + r;
            if (xr < 28) {
                int c = (nb + ni) * 16 + ln;
                Ppart[((size_t)(bb * NT + tile) * 28 + xr) * 64 + c] = acc[ni][r];
            }
        }
    }
}

// ---------------------------------------------------------------------------
// fc0 + proj0 + prep, one dispatch. v output is packed u32.
// ---------------------------------------------------------------------------
__global__ __launch_bounds__(256, 4) void fc0proj_kernel(
    const float* __restrict__ x,
    const float* __restrict__ fc0w_0, const float* __restrict__ fc0b_0,
    const float* __restrict__ fc0w_1, const float* __restrict__ fc0b_1,
    const float* __restrict__ fc1w_0, const float* __restrict__ fc1w_1,
    const unsigned short* __restrict__ Ahi, const unsigned short* __restrict__ Alo,
    unsigned int* __restrict__ v0, unsigned int* __restrict__ v1,
    unsigned short* __restrict__ w1hi, unsigned short* __restrict__ w1lo,
    unsigned short* __restrict__ Dhi,  unsigned short* __restrict__ Dlo,
    float* __restrict__ Ppart)
{
    const int t = threadIdx.x;
    if (blockIdx.x >= 2048) {
        const int gid = (blockIdx.x - 2048) * 256 + t;
        for (int idx = gid; idx < 16384; idx += 2048) {
            int br = idx >> 13, r = idx & 8191;
            int h = r >> 6, c = r & 63;
            float f = (br ? fc1w_1 : fc1w_0)[c * 128 + h];
            unsigned short hh = f2bf(f);
            w1hi[idx] = hh;
            w1lo[idx] = f2bf(f - bf2f(hh));
        }
        for (int idx = gid; idx < 32768; idx += 2048) {
            int bb = idx >> 8, o = (idx >> 2) & 63, j = idx & 3;
            Dhi[bb * 2048 + o * 32 + 28 + j] = 0;
            Dlo[bb * 2048 + o * 32 + 28 + j] = 0;
        }
        return;
    }

    __shared__ unsigned short Phi[4096];
    __shared__ unsigned short Plo[4096];
    const int bb   = blockIdx.x >> 4;
    const int tile = blockIdx.x & 15;
    const int br = bb >> 6, b = bb & 63;
    const int s0 = tile << 6;
    const float* fc0w = br ? fc0w_1 : fc0w_0;
    const float* fc0b = br ? fc0b_1 : fc0b_0;
    unsigned int* vpk = br ? v1 : v0;
    const size_t base = ((size_t)b * SLEN + s0) * 64;

    for (int idx = t; idx < 4096; idx += 256) {
        int s = idx >> 6, c = idx & 63;
        float val = x[b * SLEN + s0 + s] * fc0w[c]
                  + (float)(s0 + s) * (1.0f / 1023.0f) * fc0w[WCH + c] + fc0b[c];
        unsigned short h = f2bf(val);
        unsigned short l = f2bf(val - bf2f(h));
        vpk[base + idx] = (unsigned int)h | ((unsigned int)l << 16);
        int a = swz(c, s);
        Phi[a] = h;
        Plo[a] = l;
    }
    __syncthreads();
    proj_mfma(Phi, Plo, Ahi, Alo, Ppart, bb, tile, s0, t);
}

// ---------------------------------------------------------------------------
// Mix (per layer).
// ---------------------------------------------------------------------------
__global__ __launch_bounds__(256) void mix_kernel(
    const float* __restrict__ Ppart,
    const float* __restrict__ w1_0, const float* __restrict__ w2_0,
    const float* __restrict__ w1_1, const float* __restrict__ w2_1,
    const float* __restrict__ cw_0, const float* __restrict__ cw_1,
    unsigned short* __restrict__ cwPhi, unsigned short* __restrict__ cwPlo,
    unsigned short* __restrict__ Dhi, unsigned short* __restrict__ Dlo)
{
    const int t = threadIdx.x;
    const int br  = blockIdx.x / 225;
    const int sub = blockIdx.x % 225;

    if (sub == 224) {
        const float* cw = br ? cw_1 : cw_0;
        for (int idx = t; idx < 4096; idx += 256) {
            int k = idx >> 6, o = idx & 63;
            float val = cw[o * 64 + k] + ((k == o) ? 1.0f : 0.0f);
            unsigned short h = f2bf(val);
            cwPhi[br * 4096 + o * 64 + k] = h;
            cwPlo[br * 4096 + o * 64 + k] = f2bf(val - bf2f(h));
        }
        return;
    }

    __shared__ float Ws[64][65];
    __shared__ float LO[8][64];
    const int o = t & 63;
    const int w = t >> 6;
    const int x  = sub >> 3;
    const int b0 = (sub & 7) << 3;

    const float* wbase = (x < 14) ? (br ? w1_1 : w1_0) : (br ? w2_1 : w2_0);
    const int xi = (x < 14) ? x : (x - 14);
    for (int idx = t; idx < 4096; idx += 256)
        Ws[idx >> 6][idx & 63] = wbase[(size_t)idx * 14 + xi];

#pragma unroll
    for (int j = 0; j < 2; ++j) {
        int bi = w + 4 * j;
        int bb = br * 64 + b0 + bi;
        float s = 0.f;
        for (int tile = 0; tile < NT; ++tile)
            s += Ppart[((size_t)(bb * NT + tile) * 28 + x) * 64 + o];
        LO[bi][o] = s;
    }
    __syncthreads();

#pragma unroll
    for (int j = 0; j < 2; ++j) {
        int bi = w + 4 * j;
        int bb = br * 64 + b0 + bi;
        float acc = 0.f;
        for (int i = 0; i < 64; ++i)
            acc += LO[bi][i] * Ws[i][o];
        acc -= LO[bi][o];
        unsigned short h = f2bf(acc);
        Dhi[bb * 2048 + o * 32 + x] = h;
        Dlo[bb * 2048 + o * 32 + x] = f2bf(acc - bf2f(h));
    }
}

// ---------------------------------------------------------------------------
// Fused layer (i = 0,1,2): 128-thread blocks, 2 waves per 64-s tile, each wave
// owns a 32-o half. B frags register-resident; packed v in/out; proj reads
// only own wave's c-half -> NO barriers. grid 2048.
// ---------------------------------------------------------------------------
__global__ __launch_bounds__(128, 3) void layer_kernel(
    const unsigned int* __restrict__ vin0, const unsigned int* __restrict__ vin1,
    unsigned int* __restrict__ vout0, unsigned int* __restrict__ vout1,
    const unsigned short* __restrict__ MThi, const unsigned short* __restrict__ MTlo,
    const unsigned short* __restrict__ Ahi,  const unsigned short* __restrict__ Alo,
    const unsigned short* __restrict__ cwPhi, const unsigned short* __restrict__ cwPlo,
    const unsigned short* __restrict__ Dhi,   const unsigned short* __restrict__ Dlo,
    const float* __restrict__ cb_0, const float* __restrict__ cb_1,
    float* __restrict__ Ppart)
{
    __shared__ unsigned short Phi[4096];   // block-shared swizzled [c][s64]
    __shared__ unsigned short Plo[4096];

    const int t = threadIdx.x;
    const int bid = blockIdx.x;
    const int br  = bid >> 10;
    const int rem = bid & 1023;
    const int b    = rem >> 4;
    const int tile = rem & 15;
    const int s0   = tile << 6;
    const size_t bS = (size_t)b * SLEN;
    const unsigned int* vin = br ? vin1 : vin0;
    unsigned int* vout      = br ? vout1 : vout0;
    const float* cb = br ? cb_1 : cb_0;
    const int bb = br * 64 + b;

    const int lane = t & 63;
    const int w    = t >> 6;          // 0..1: o-half
    const int qr   = lane >> 4;
    const int ln   = lane & 15;

    // ---- preload B fragments for this wave's o-half ----
    s16x8 Bh[2][2], Bl[2][2];
#pragma unroll
    for (int kk = 0; kk < 2; ++kk)
#pragma unroll
        for (int ni = 0; ni < 2; ++ni) {
            const int o = w * 32 + ni * 16 + ln;
            const int boff = br * 4096 + o * 64 + kk * 32 + qr * 8;
            Bh[kk][ni] = *(const s16x8*)&cwPhi[boff];
            Bl[kk][ni] = *(const s16x8*)&cwPlo[boff];
        }
    s16x8 Dhf[2], Dlf[2];
#pragma unroll
    for (int ni = 0; ni < 2; ++ni) {
        const int o = w * 32 + ni * 16 + ln;
        const int boff = bb * 2048 + o * 32 + qr * 8;
        Dhf[ni] = *(const s16x8*)&Dhi[boff];
        Dlf[ni] = *(const s16x8*)&Dlo[boff];
    }
    float cbv[2];
#pragma unroll
    for (int ni = 0; ni < 2; ++ni) cbv[ni] = cb[w * 32 + ni * 16 + ln];

    // ---- 4 m-tiles ----
#pragma unroll
    for (int mi = 0; mi < 4; ++mi) {
        const int srow = mi * 16 + ln;
        f32x4 acc[2];
        acc[0] = (f32x4){0.f,0.f,0.f,0.f};
        acc[1] = (f32x4){0.f,0.f,0.f,0.f};

#pragma unroll
        for (int kk = 0; kk < 2; ++kk) {
            const size_t aoff = (bS + s0 + srow) * 64 + kk * 32 + qr * 8;
            s16x8 ah, al;
            unpack_frag(&vin[aoff], &ah, &al);
#pragma unroll
            for (int ni = 0; ni < 2; ++ni) {
                acc[ni] = __builtin_amdgcn_mfma_f32_16x16x32_bf16(ah, Bh[kk][ni], acc[ni], 0, 0, 0);
                acc[ni] = __builtin_amdgcn_mfma_f32_16x16x32_bf16(al, Bh[kk][ni], acc[ni], 0, 0, 0);
                acc[ni] = __builtin_amdgcn_mfma_f32_16x16x32_bf16(ah, Bl[kk][ni], acc[ni], 0, 0, 0);
            }
        }
        {
            const size_t aoff = (size_t)(s0 + srow) * 32 + qr * 8;
            s16x8 ah = *(const s16x8*)&MThi[aoff];
            s16x8 al = *(const s16x8*)&MTlo[aoff];
#pragma unroll
            for (int ni = 0; ni < 2; ++ni) {
                acc[ni] = __builtin_amdgcn_mfma_f32_16x16x32_bf16(ah, Dhf[ni], acc[ni], 0, 0, 0);
                acc[ni] = __builtin_amdgcn_mfma_f32_16x16x32_bf16(al, Dhf[ni], acc[ni], 0, 0, 0);
                acc[ni] = __builtin_amdgcn_mfma_f32_16x16x32_bf16(ah, Dlf[ni], acc[ni], 0, 0, 0);
            }
        }
        // epilogue: gelu, split, packed global store + LDS (own c-half)
#pragma unroll
        for (int ni = 0; ni < 2; ++ni) {
            const int o = w * 32 + ni * 16 + ln;
#pragma unroll
            for (int r = 0; r < 4; ++r) {
                const int sl64 = mi * 16 + qr * 4 + r;
                float val = gelu_f(acc[ni][r] + cbv[ni]);
                unsigned short h = f2bf(val);
                unsigned short l = f2bf(val - bf2f(h));
                vout[(bS + s0 + sl64) * 64 + o] =
                    (unsigned int)h | ((unsigned int)l << 16);
                const int a = swz(o, sl64);
                Phi[a] = h;
                Plo[a] = l;
            }
        }
    }

    // ---- proj on own c-half (same-wave LDS RAW: no barrier needed) ----
    f32x4 pacc[2][2];
#pragma unroll
    for (int mt = 0; mt < 2; ++mt)
#pragma unroll
        for (int ni = 0; ni < 2; ++ni) pacc[mt][ni] = (f32x4){0.f,0.f,0.f,0.f};

#pragma unroll
    for (int kk = 0; kk < 2; ++kk) {
        const int bk = kk * 4 + qr;
        s16x8 pah[2], pal[2];
#pragma unroll
        for (int mt = 0; mt < 2; ++mt) {
            const int arow = (mt * 16 + ln) * SLEN + s0 + kk * 32 + qr * 8;
            pah[mt] = *(const s16x8*)&Ahi[arow];
            pal[mt] = *(const s16x8*)&Alo[arow];
        }
#pragma unroll
        for (int ni = 0; ni < 2; ++ni) {
            const int c = w * 32 + ni * 16 + ln;
            const int boff = c * 64 + ((bk ^ (c & 7)) << 3);
            s16x8 bh = *(const s16x8*)&Phi[boff];
            s16x8 bl = *(const s16x8*)&Plo[boff];
#pragma unroll
            for (int mt = 0; mt < 2; ++mt) {
                pacc[mt][ni] = __builtin_amdgcn_mfma_f32_16x16x32_bf16(pah[mt], bh, pacc[mt][ni], 0, 0, 0);
                pacc[mt][ni] = __builtin_amdgcn_mfma_f32_16x16x32_bf16(pal[mt], bh, pacc[mt][ni], 0, 0, 0);
                pacc[mt][ni] = __builtin_amdgcn_mfma_f32_16x16x32_bf16(pah[mt], bl, pacc[mt][ni], 0, 0, 0);
            }
        }
    }
#pragma unroll
    for (int mt = 0; mt < 2; ++mt)
#pragma unroll
        for (int ni = 0; ni < 2; ++ni) {
            const int c = w * 32 + ni * 16 + ln;
#pragma unroll
            for (int r = 0; r < 4; ++r) {
                const int xr = mt * 16 + qr * 4 + r;
                if (xr < 28)
                    Ppart[((size_t)(bb * NT + tile) * 28 + xr) * 64 + c] = pacc[mt][ni][r];
            }
        }
}

// ---------------------------------------------------------------------------
// Head with fused layer 3: 128-thread blocks (2 waves per 64-s tile).
// Packed v input. Phase A per-wave 32-o half -> shared LDS, one barrier.
// Phase B: 64-h half of fc1, gelu*fc2, shfl-reduce, atomicAdd into out.
// ---------------------------------------------------------------------------
__global__ __launch_bounds__(128, 3) void head_kernel(
    const unsigned int* __restrict__ vin0, const unsigned int* __restrict__ vin1,
    const unsigned short* __restrict__ MThi, const unsigned short* __restrict__ MTlo,
    const unsigned short* __restrict__ cwPhi, const unsigned short* __restrict__ cwPlo,
    const unsigned short* __restrict__ Dhi,   const unsigned short* __restrict__ Dlo,
    const float* __restrict__ cb_0, const float* __restrict__ cb_1,
    const unsigned short* __restrict__ w1hi, const unsigned short* __restrict__ w1lo,
    const float* __restrict__ fc1b_0, const float* __restrict__ fc2w_0,
    const float* __restrict__ fc2b_0,
    const float* __restrict__ fc1b_1, const float* __restrict__ fc2w_1,
    const float* __restrict__ fc2b_1,
    float* __restrict__ out)
{
    __shared__ unsigned short Vh[4096];    // block-shared swz2 [s64][c]
    __shared__ unsigned short Vl[4096];

    const int t = threadIdx.x;
    const int bid = blockIdx.x;
    const int br  = bid >> 10;
    const int rem = bid & 1023;
    const int b    = rem >> 4;
    const int tile = rem & 15;
    const int s0   = tile << 6;
    const size_t bS = (size_t)b * SLEN;

    const int lane = t & 63;
    const int w    = t >> 6;          // 0..1
    const int qr   = lane >> 4;
    const int ln   = lane & 15;

    const unsigned int* vin = br ? vin1 : vin0;
    const float* cb   = br ? cb_1 : cb_0;
    const float* fc1b = br ? fc1b_1 : fc1b_0;
    const float* fc2w = br ? fc2w_1 : fc2w_0;
    const float fc2b  = (br ? fc2b_1 : fc2b_0)[0];
    const int bb = br * 64 + b;

    // ---- phase A: layer-3, own 32-o half ----
    {
        s16x8 Bh[2][2], Bl[2][2];
#pragma unroll
        for (int kk = 0; kk < 2; ++kk)
#pragma unroll
            for (int ni = 0; ni < 2; ++ni) {
                const int o = w * 32 + ni * 16 + ln;
                const int boff = br * 4096 + o * 64 + kk * 32 + qr * 8;
                Bh[kk][ni] = *(const s16x8*)&cwPhi[boff];
                Bl[kk][ni] = *(const s16x8*)&cwPlo[boff];
            }
        s16x8 Dhf[2], Dlf[2];
#pragma unroll
        for (int ni = 0; ni < 2; ++ni) {
            const int o = w * 32 + ni * 16 + ln;
            const int boff = bb * 2048 + o * 32 + qr * 8;
            Dhf[ni] = *(const s16x8*)&Dhi[boff];
            Dlf[ni] = *(const s16x8*)&Dlo[boff];
        }
        float cbv[2];
#pragma unroll
        for (int ni = 0; ni < 2; ++ni) cbv[ni] = cb[w * 32 + ni * 16 + ln];

#pragma unroll
        for (int mi = 0; mi < 4; ++mi) {
            const int srow = mi * 16 + ln;
            f32x4 acc[2];
            acc[0] = (f32x4){0.f,0.f,0.f,0.f};
            acc[1] = (f32x4){0.f,0.f,0.f,0.f};

#pragma unroll
            for (int kk = 0; kk < 2; ++kk) {
                const size_t aoff = (bS + s0 + srow) * 64 + kk * 32 + qr * 8;
                s16x8 ah, al;
                unpack_frag(&vin[aoff], &ah, &al);
#pragma unroll
                for (int ni = 0; ni < 2; ++ni) {
                    acc[ni] = __builtin_amdgcn_mfma_f32_16x16x32_bf16(ah, Bh[kk][ni], acc[ni], 0, 0, 0);
                    acc[ni] = __builtin_amdgcn_mfma_f32_16x16x32_bf16(al, Bh[kk][ni], acc[ni], 0, 0, 0);
                    acc[ni] = __builtin_amdgcn_mfma_f32_16x16x32_bf16(ah, Bl[kk][ni], acc[ni], 0, 0, 0);
                }
            }
            {
                const size_t aoff = (size_t)(s0 + srow) * 32 + qr * 8;
                s16x8 ah = *(const s16x8*)&MThi[aoff];
                s16x8 al = *(const s16x8*)&MTlo[aoff];
#pragma unroll
                for (int ni = 0; ni < 2; ++ni) {
                    acc[ni] = __builtin_amdgcn_mfma_f32_16x16x32_bf16(ah, Dhf[ni], acc[ni], 0, 0, 0);
                    acc[ni] = __builtin_amdgcn_mfma_f32_16x16x32_bf16(al, Dhf[ni], acc[ni], 0, 0, 0);
                    acc[ni] = __builtin_amdgcn_mfma_f32_16x16x32_bf16(ah, Dlf[ni], acc[ni], 0, 0, 0);
                }
            }
#pragma unroll
            for (int ni = 0; ni < 2; ++ni) {
                const int o = w * 32 + ni * 16 + ln;
#pragma unroll
                for (int r = 0; r < 4; ++r) {
                    const int sl64 = mi * 16 + qr * 4 + r;
                    float val = acc[ni][r] + cbv[ni];
                    unsigned short h = f2bf(val);
                    unsigned short l = f2bf(val - bf2f(h));
                    const int a = swz2(sl64, o);
                    Vh[a] = h;
                    Vl[a] = l;
                }
            }
        }
    }
    __syncthreads();

    // ---- phase B: fc1 GEMM, own 64-h half ----
    s16x8 Wh[2][4], Wl[2][4];
#pragma unroll
    for (int kk = 0; kk < 2; ++kk)
#pragma unroll
        for (int ni = 0; ni < 4; ++ni) {
            const int h = w * 64 + ni * 16 + ln;
            const int boff = br * 8192 + h * 64 + kk * 32 + qr * 8;
            Wh[kk][ni] = *(const s16x8*)&w1hi[boff];
            Wl[kk][ni] = *(const s16x8*)&w1lo[boff];
        }
    float b1v[4], w2v[4];
#pragma unroll
    for (int ni = 0; ni < 4; ++ni) {
        b1v[ni] = fc1b[w * 64 + ni * 16 + ln];
        w2v[ni] = fc2w[w * 64 + ni * 16 + ln];
    }

#pragma unroll
    for (int mi = 0; mi < 4; ++mi) {
        f32x4 acc1[4];
#pragma unroll
        for (int ni = 0; ni < 4; ++ni) acc1[ni] = (f32x4){0.f,0.f,0.f,0.f};

#pragma unroll
        for (int kk = 0; kk < 2; ++kk) {
            const int blk = kk * 4 + qr;
            const int sl  = mi * 16 + ln;
            const int a   = sl * 64 + ((blk ^ (sl & 7)) << 3);
            s16x8 ah = *(const s16x8*)&Vh[a];
            s16x8 al = *(const s16x8*)&Vl[a];
#pragma unroll
            for (int ni = 0; ni < 4; ++ni) {
                acc1[ni] = __builtin_amdgcn_mfma_f32_16x16x32_bf16(ah, Wh[kk][ni], acc1[ni], 0, 0, 0);
                acc1[ni] = __builtin_amdgcn_mfma_f32_16x16x32_bf16(al, Wh[kk][ni], acc1[ni], 0, 0, 0);
                acc1[ni] = __builtin_amdgcn_mfma_f32_16x16x32_bf16(ah, Wl[kk][ni], acc1[ni], 0, 0, 0);
            }
        }
        float partial[4] = {0.f, 0.f, 0.f, 0.f};
#pragma unroll
        for (int ni = 0; ni < 4; ++ni) {
#pragma unroll
            for (int r = 0; r < 4; ++r)
                partial[r] += gelu_f(acc1[ni][r] + b1v[ni]) * w2v[ni];
        }
#pragma unroll
        for (int r = 0; r < 4; ++r) {
            partial[r] += __shfl_xor(partial[r], 1, 64);
            partial[r] += __shfl_xor(partial[r], 2, 64);
            partial[r] += __shfl_xor(partial[r], 4, 64);
            partial[r] += __shfl_xor(partial[r], 8, 64);
        }
        if (ln == 0) {
            const float bias = (w == 0) ? fc2b : 0.f;
#pragma unroll
            for (int r = 0; r < 4; ++r)
                atomicAdd(&out[bS + s0 + mi * 16 + qr * 4 + r],
                          partial[r] + bias);
        }
    }
}

// ---------------------------------------------------------------------------
extern "C" void kernel_launch(void* const* d_in, const int* in_sizes, int n_in,
                              void* d_out, int out_size, void* d_ws, size_t ws_size,
                              hipStream_t stream)
{
    const float* x = (const float*)d_in[0];
    const float* P[2][10];
    for (int br = 0; br < 2; ++br)
        for (int k = 0; k < 10; ++k)
            P[br][k] = (const float*)d_in[1 + br * 10 + k];
    // order: fc0_w, fc0_b, wave_w1, wave_w2, cw, cb, fc1_w, fc1_b, fc2_w, fc2_b

    char* p = (char*)d_ws;
    const size_t PL = (size_t)BC * SLEN * 4;   // one packed u32 plane: 16.78 MB
    unsigned int* vplane[4];                   // [br][pingpong]
    for (int i = 0; i < 4; ++i) { vplane[i] = (unsigned int*)p; p += PL; }
    unsigned short* Ahi  = (unsigned short*)p; p += 32 * SLEN * 2;
    unsigned short* Alo  = (unsigned short*)p; p += 32 * SLEN * 2;
    unsigned short* MThi = (unsigned short*)p; p += SLEN * 32 * 2;
    unsigned short* MTlo = (unsigned short*)p; p += SLEN * 32 * 2;
    float* Ppart = (float*)p;                  p += (size_t)128 * NT * 28 * 64 * 4;
    unsigned short* cwPhi = (unsigned short*)p; p += 2 * 4096 * 2;
    unsigned short* cwPlo = (unsigned short*)p; p += 2 * 4096 * 2;
    unsigned short* Dhi   = (unsigned short*)p; p += (size_t)128 * 2048 * 2;
    unsigned short* Dlo   = (unsigned short*)p; p += (size_t)128 * 2048 * 2;
    unsigned short* w1hi  = (unsigned short*)p; p += 2 * 8192 * 2;
    unsigned short* w1lo  = (unsigned short*)p; p += 2 * 8192 * 2;

    unsigned int *v0a = vplane[0], *v0b = vplane[1];
    unsigned int *v1a = vplane[2], *v1b = vplane[3];

    precompute_kernel<<<284, 256, 0, stream>>>(Ahi, Alo, MThi, MTlo);

    hipMemsetAsync(d_out, 0, (size_t)out_size * sizeof(float), stream);

    fc0proj_kernel<<<2056, 256, 0, stream>>>(
        x, P[0][0], P[0][1], P[1][0], P[1][1], P[0][6], P[1][6],
        Ahi, Alo, v0a, v1a, w1hi, w1lo, Dhi, Dlo, Ppart);

    for (int i = 0; i < 3; ++i) {
        mix_kernel<<<450, 256, 0, stream>>>(
            Ppart,
            P[0][2] + (size_t)i * WCH * WCH * 14, P[0][3] + (size_t)i * WCH * WCH * 14,
            P[1][2] + (size_t)i * WCH * WCH * 14, P[1][3] + (size_t)i * WCH * WCH * 14,
            P[0][4] + (size_t)i * WCH * WCH,      P[1][4] + (size_t)i * WCH * WCH,
            cwPhi, cwPlo, Dhi, Dlo);
        layer_kernel<<<2048, 128, 0, stream>>>(
            v0a, v1a, v0b, v1b,
            MThi, MTlo, Ahi, Alo, cwPhi, cwPlo, Dhi, Dlo,
            P[0][5] + (size_t)i * WCH, P[1][5] + (size_t)i * WCH,
            Ppart);
        unsigned int* tmp;
        tmp = v0a; v0a = v0b; v0b = tmp;
        tmp = v1a; v1a = v1b; v1b = tmp;
    }

    mix_kernel<<<450, 256, 0, stream>>>(
        Ppart,
        P[0][2] + (size_t)3 * WCH * WCH * 14, P[0][3] + (size_t)3 * WCH * WCH * 14,
        P[1][2] + (size_t)3 * WCH * WCH * 14, P[1][3] + (size_t)3 * WCH * WCH * 14,
        P[0][4] + (size_t)3 * WCH * WCH,      P[1][4] + (size_t)3 * WCH * WCH,
        cwPhi, cwPlo, Dhi, Dlo);

    head_kernel<<<2048, 128, 0, stream>>>(
        v0a, v1a,
        MThi, MTlo, cwPhi, cwPlo, Dhi, Dlo,
        P[0][5] + (size_t)3 * WCH, P[1][5] + (size_t)3 * WCH,
        w1hi, w1lo,
        P[0][7], P[0][8], P[0][9],
        P[1][7], P[1][8], P[1][9],
        (float*)d_out);
}

// Round 18
// 283.203 us; speedup vs baseline: 1.0483x; 1.0044x over previous
//
#include <hip/hip_runtime.h>
#include <hip/hip_bf16.h>
#include <math.h>

// ---------------------------------------------------------------------------
// WNO1d. wave_conv(v) = v + Syn(W1*lo8-lo8, W2*hi8-hi8)  (perfect reconstruction;
// intermediate highs pass through). Constant operators, computed on device:
//   A  (28x1024 analysis)  -> split-bf16 planes Ahi/Alo [32][1024] (pad rows 0)
//   M^T(28x1024 synthesis) -> split-bf16 planes MThi/MTlo [1024][32] (pad 0)
// Activations: PACKED split-bf16 planes v[b][s][c] as u32 = hi | lo<<16.
// All GEMMs on MFMA (split-bf16 3-mfma = fp32-grade).
// Round 18: precompute A-part re-parallelized (1 column per 256-thr block,
// 1024 blocks); cwT(+I) split for ALL 4 layers hoisted into fc0proj prep
// (cwP planes [L][br]); mix slimmed to 448 uniform blocks.
// ---------------------------------------------------------------------------

#define BDIM 64
#define SLEN 1024
#define WCH  64
#define BC   (BDIM*WCH)
#define NT   16         // 64-s proj tiles per batch

typedef short s16x8 __attribute__((ext_vector_type(8)));
typedef float f32x4 __attribute__((ext_vector_type(4)));

constexpr float RLv[12] = {
    0.11154074335008017f, 0.4946238903983854f, 0.7511339080215775f,
    0.3152503517092432f, -0.22626469396516913f, -0.12976686756709563f,
    0.09750160558707936f, 0.02752286553001629f, -0.031582039318031156f,
    0.0005538422009938016f, 0.004777257511010651f, -0.00107730108499558f };
constexpr float AHv[12] = {
     RLv[11], -RLv[10],  RLv[9], -RLv[8],  RLv[7], -RLv[6],
     RLv[5],  -RLv[4],   RLv[3], -RLv[2],  RLv[1], -RLv[0] };
constexpr float SLv[12] = {
     RLv[11], RLv[10], RLv[9], RLv[8], RLv[7], RLv[6],
     RLv[5],  RLv[4],  RLv[3], RLv[2], RLv[1], RLv[0] };
constexpr float SHv[12] = {
    -RLv[0],  RLv[1], -RLv[2],  RLv[3], -RLv[4],  RLv[5],
    -RLv[6],  RLv[7], -RLv[8],  RLv[9], -RLv[10], RLv[11] };

// fast gelu: x * sigmoid(2*0.79788*(x+0.044715x^3)); <=~4e-4 dev/application.
__device__ __forceinline__ float gelu_f(float x) {
    float z = 0.7978845608f * (x + 0.044715f * x * x * x);
    return x / (1.0f + __expf(-2.0f * z));
}
__device__ __forceinline__ unsigned short f2bf(float f) {
    __hip_bfloat16 h = __float2bfloat16(f);
    union { __hip_bfloat16 h; unsigned short u; } cv; cv.h = h; return cv.u;
}
__device__ __forceinline__ float bf2f(unsigned short u) {
    union { unsigned short u; __hip_bfloat16 h; } cv; cv.u = u;
    return __bfloat162float(cv.h);
}
// unpack 8 consecutive packed u32 -> hi frag + lo frag (8 v_perm)
__device__ __forceinline__ void unpack_frag(const unsigned int* p8,
                                            s16x8* ah, s16x8* al) {
    uint4 a = *(const uint4*)p8;
    uint4 b = *(const uint4*)(p8 + 4);
    union { s16x8 v; unsigned int d[4]; } H, L;
    H.d[0] = __builtin_amdgcn_perm(a.y, a.x, 0x05040100u);
    H.d[1] = __builtin_amdgcn_perm(a.w, a.z, 0x05040100u);
    H.d[2] = __builtin_amdgcn_perm(b.y, b.x, 0x05040100u);
    H.d[3] = __builtin_amdgcn_perm(b.w, b.z, 0x05040100u);
    L.d[0] = __builtin_amdgcn_perm(a.y, a.x, 0x07060302u);
    L.d[1] = __builtin_amdgcn_perm(a.w, a.z, 0x07060302u);
    L.d[2] = __builtin_amdgcn_perm(b.y, b.x, 0x07060302u);
    L.d[3] = __builtin_amdgcn_perm(b.w, b.z, 0x07060302u);
    *ah = H.v; *al = L.v;
}

// swizzled [c][s] plane (64x64 shorts): 16B blocks XORed -> aligned b128 frags
__device__ __forceinline__ int swz(int c, int s) {
    return c * 64 + ((((s >> 3) ^ (c & 7)) << 3) | (s & 7));
}
// swizzled [s][c] plane
__device__ __forceinline__ int swz2(int s, int c) {
    return s * 64 + ((((c >> 3) ^ (s & 7)) << 3) | (c & 7));
}

// ---------------------------------------------------------------------------
// precompute: blocks 0..1023 -> A column s0 (256 threads each);
//             blocks 1024..1051 -> M row u.
// ---------------------------------------------------------------------------
__global__ __launch_bounds__(256) void precompute_kernel(
    unsigned short* __restrict__ Ahi, unsigned short* __restrict__ Alo,
    unsigned short* __restrict__ MThi, unsigned short* __restrict__ MTlo)
{
    __shared__ float Af[1024];
    __shared__ float Bff[520];
    __shared__ float hib[14];
    const int t = threadIdx.x;

    if (blockIdx.x < 1024) {
        const int s0 = blockIdx.x;
        for (int i = t; i < SLEN; i += 256) Af[i] = (i == s0) ? 1.0f : 0.0f;
        __syncthreads();

        const int NIN[8]  = {1024, 517, 264, 137, 74, 42, 26, 18};
        const int NOUT[8] = { 517, 264, 137,  74, 42, 26, 18, 14};
#pragma unroll
        for (int lev = 0; lev < 8; ++lev) {
            float* in  = (lev & 1) ? Bff : Af;
            float* out = (lev & 1) ? Af : Bff;
            const int nin = NIN[lev], nout = NOUT[lev];
            for (int m = t; m < nout; m += 256) {
                float alo = 0.f, ahi = 0.f;
#pragma unroll
                for (int tt = 0; tt < 12; ++tt) {
                    int jj = 2 * m + tt - 10;
                    if (jj < 0)         jj = -1 - jj;
                    else if (jj >= nin) jj = 2 * nin - 1 - jj;
                    float xv = in[jj];
                    alo += xv * RLv[tt];
                    if (lev == 7) ahi += xv * AHv[tt];
                }
                out[m] = alo;
                if (lev == 7) {
                    unsigned short h1 = f2bf(alo);
                    Ahi[m * SLEN + s0] = h1;
                    Alo[m * SLEN + s0] = f2bf(alo - bf2f(h1));
                    unsigned short h2 = f2bf(ahi);
                    Ahi[(14 + m) * SLEN + s0] = h2;
                    Alo[(14 + m) * SLEN + s0] = f2bf(ahi - bf2f(h2));
                }
            }
            __syncthreads();
        }
        if (t < 4) {
            Ahi[(28 + t) * SLEN + s0] = 0; Alo[(28 + t) * SLEN + s0] = 0;
            MThi[s0 * 32 + 28 + t] = 0;    MTlo[s0 * 32 + 28 + t] = 0;
        }
        return;
    }

    const int u = blockIdx.x - 1024;     // 0..27
    if (t < 14) {
        Af[t]  = (u < 14 && t == u) ? 1.0f : 0.0f;
        hib[t] = (u >= 14 && t == (u - 14)) ? 1.0f : 0.0f;
    }
    __syncthreads();

    const int NH[8] = {14, 18, 26, 42, 74, 137, 264, 517};
    const int NO[8] = {18, 26, 42, 74, 138, 264, 518, 1024};

#pragma unroll
    for (int s = 0; s < 8; ++s) {
        const float* lo = (s & 1) ? Bff : Af;
        float* out      = (s & 1) ? Af : Bff;
        const int N = NH[s], nout = NO[s];
        for (int m = t; m < nout; m += 256) {
            float acc = 0.f;
#pragma unroll
            for (int tt = 0; tt < 12; ++tt) {
                int uu = m + tt - 1;
                if ((uu & 1) == 0) {
                    int q = uu >> 1;
                    if (q < N) {
                        acc += lo[q] * SLv[tt];
                        if (s == 0) acc += hib[q] * SHv[tt];
                    }
                }
            }
            out[m] = acc;
        }
        __syncthreads();
    }
    for (int m = t; m < SLEN; m += 256) {
        float f = Af[m];
        unsigned short h = f2bf(f);
        MThi[m * 32 + u] = h;
        MTlo[m * 32 + u] = f2bf(f - bf2f(h));
    }
}

// ---------------------------------------------------------------------------
// proj-MFMA body for barrier-style 64-s blocks (fc0proj only, 256 threads).
// ---------------------------------------------------------------------------
__device__ __forceinline__ void proj_mfma(
    const unsigned short* Phi, const unsigned short* Plo,
    const unsigned short* __restrict__ Ahi, const unsigned short* __restrict__ Alo,
    float* __restrict__ Ppart, int bb, int tile, int s0, int t)
{
    const int lane = t & 63;
    const int w    = t >> 6;
    const int qr   = lane >> 4;
    const int ln   = lane & 15;
    const int mt   = w >> 1;
    const int nb   = (w & 1) * 2;

    f32x4 acc[2];
    acc[0] = (f32x4){0.f,0.f,0.f,0.f};
    acc[1] = (f32x4){0.f,0.f,0.f,0.f};

#pragma unroll
    for (int kk = 0; kk < 2; ++kk) {
        const int k0 = kk * 32;
        const int arow = (mt * 16 + ln) * SLEN + s0 + k0 + qr * 8;
        s16x8 ah = *(const s16x8*)&Ahi[arow];
        s16x8 al = *(const s16x8*)&Alo[arow];
        const int bk = (k0 >> 3) + qr;
#pragma unroll
        for (int ni = 0; ni < 2; ++ni) {
            const int c = (nb + ni) * 16 + ln;
            const int boff = c * 64 + (((bk ^ (c & 7)) << 3));
            s16x8 bh = *(const s16x8*)&Phi[boff];
            s16x8 bl = *(const s16x8*)&Plo[boff];
            acc[ni] = __builtin_amdgcn_mfma_f32_16x16x32_bf16(ah, bh, acc[ni], 0, 0, 0);
            acc[ni] = __builtin_amdgcn_mfma_f32_16x16x32_bf16(al, bh, acc[ni], 0, 0, 0);
            acc[ni] = __builtin_amdgcn_mfma_f32_16x16x32_bf16(ah, bl, acc[ni], 0, 0, 0);
        }
    }
#pragma unroll
    for (int ni = 0; ni < 2; ++ni) {
#pragma unroll
        for (int r = 0; r < 4; ++r) {
            int xr = mt * 16 + qr * 4 + r;
            if (xr < 28) {
                int c = (nb + ni) * 16 + ln;
                Ppart[((size_t)(bb * NT + tile) * 28 + xr) * 64 + c] = acc[ni][r];
            }
        }
    }
}

// ---------------------------------------------------------------------------
// fc0 + proj0 + prep, one dispatch. v output is packed u32.
// Prep blocks also split cwT(+I) for ALL 4 layers into cwP[L][br] planes.
// ---------------------------------------------------------------------------
__global__ __launch_bounds__(256, 4) void fc0proj_kernel(
    const float* __restrict__ x,
    const float* __restrict__ fc0w_0, const float* __restrict__ fc0b_0,
    const float* __restrict__ fc0w_1, const float* __restrict__ fc0b_1,
    const float* __restrict__ fc1w_0, const float* __restrict__ fc1w_1,
    const float* __restrict__ cw_0, const float* __restrict__ cw_1,
    const unsigned short* __restrict__ Ahi, const unsigned short* __restrict__ Alo,
    unsigned int* __restrict__ v0, unsigned int* __restrict__ v1,
    unsigned short* __restrict__ w1hi, unsigned short* __restrict__ w1lo,
    unsigned short* __restrict__ cwPhi, unsigned short* __restrict__ cwPlo,
    unsigned short* __restrict__ Dhi,  unsigned short* __restrict__ Dlo,
    float* __restrict__ Ppart)
{
    const int t = threadIdx.x;
    if (blockIdx.x >= 2048) {
        const int gid = (blockIdx.x - 2048) * 256 + t;
        for (int idx = gid; idx < 16384; idx += 2048) {
            int br = idx >> 13, r = idx & 8191;
            int h = r >> 6, c = r & 63;
            float f = (br ? fc1w_1 : fc1w_0)[c * 128 + h];
            unsigned short hh = f2bf(f);
            w1hi[idx] = hh;
            w1lo[idx] = f2bf(f - bf2f(hh));
        }
        for (int idx = gid; idx < 32768; idx += 2048) {   // cwT split, all layers
            int L = idx >> 13, br = (idx >> 12) & 1, e = idx & 4095;
            int k = e >> 6, o = e & 63;
            float val = (br ? cw_1 : cw_0)[(size_t)L * 4096 + o * 64 + k]
                      + ((k == o) ? 1.0f : 0.0f);
            unsigned short h = f2bf(val);
            const int off = (L * 2 + br) * 4096 + o * 64 + k;
            cwPhi[off] = h;
            cwPlo[off] = f2bf(val - bf2f(h));
        }
        for (int idx = gid; idx < 32768; idx += 2048) {   // D pad rows 28..31
            int bb = idx >> 8, o = (idx >> 2) & 63, j = idx & 3;
            Dhi[bb * 2048 + o * 32 + 28 + j] = 0;
            Dlo[bb * 2048 + o * 32 + 28 + j] = 0;
        }
        return;
    }

    __shared__ unsigned short Phi[4096];
    __shared__ unsigned short Plo[4096];
    const int bb   = blockIdx.x >> 4;
    const int tile = blockIdx.x & 15;
    const int br = bb >> 6, b = bb & 63;
    const int s0 = tile << 6;
    const float* fc0w = br ? fc0w_1 : fc0w_0;
    const float* fc0b = br ? fc0b_1 : fc0b_0;
    unsigned int* vpk = br ? v1 : v0;
    const size_t base = ((size_t)b * SLEN + s0) * 64;

    for (int idx = t; idx < 4096; idx += 256) {
        int s = idx >> 6, c = idx & 63;
        float val = x[b * SLEN + s0 + s] * fc0w[c]
                  + (float)(s0 + s) * (1.0f / 1023.0f) * fc0w[WCH + c] + fc0b[c];
        unsigned short h = f2bf(val);
        unsigned short l = f2bf(val - bf2f(h));
        vpk[base + idx] = (unsigned int)h | ((unsigned int)l << 16);
        int a = swz(c, s);
        Phi[a] = h;
        Plo[a] = l;
    }
    __syncthreads();
    proj_mfma(Phi, Plo, Ahi, Alo, Ppart, bb, tile, s0, t);
}

// ---------------------------------------------------------------------------
// Mix (per layer): 448 uniform blocks (br*224 + x*8 + bgroup).
// ---------------------------------------------------------------------------
__global__ __launch_bounds__(256) void mix_kernel(
    const float* __restrict__ Ppart,
    const float* __restrict__ w1_0, const float* __restrict__ w2_0,
    const float* __restrict__ w1_1, const float* __restrict__ w2_1,
    unsigned short* __restrict__ Dhi, unsigned short* __restrict__ Dlo)
{
    const int t = threadIdx.x;
    const int br  = blockIdx.x / 224;
    const int sub = blockIdx.x % 224;

    __shared__ float Ws[64][65];
    __shared__ float LO[8][64];
    const int o = t & 63;
    const int w = t >> 6;
    const int x  = sub >> 3;
    const int b0 = (sub & 7) << 3;

    const float* wbase = (x < 14) ? (br ? w1_1 : w1_0) : (br ? w2_1 : w2_0);
    const int xi = (x < 14) ? x : (x - 14);
    for (int idx = t; idx < 4096; idx += 256)
        Ws[idx >> 6][idx & 63] = wbase[(size_t)idx * 14 + xi];

#pragma unroll
    for (int j = 0; j < 2; ++j) {
        int bi = w + 4 * j;
        int bb = br * 64 + b0 + bi;
        float s = 0.f;
        for (int tile = 0; tile < NT; ++tile)
            s += Ppart[((size_t)(bb * NT + tile) * 28 + x) * 64 + o];
        LO[bi][o] = s;
    }
    __syncthreads();

#pragma unroll
    for (int j = 0; j < 2; ++j) {
        int bi = w + 4 * j;
        int bb = br * 64 + b0 + bi;
        float acc = 0.f;
        for (int i = 0; i < 64; ++i)
            acc += LO[bi][i] * Ws[i][o];
        acc -= LO[bi][o];
        unsigned short h = f2bf(acc);
        Dhi[bb * 2048 + o * 32 + x] = h;
        Dlo[bb * 2048 + o * 32 + x] = f2bf(acc - bf2f(h));
    }
}

// ---------------------------------------------------------------------------
// Fused layer (i = 0,1,2): 128-thread blocks, 2 waves per 64-s tile, each wave
// owns a 32-o half. B frags register-resident; packed v in/out; proj reads
// only own wave's c-half -> NO barriers. grid 2048. Lidx selects cwP plane.
// ---------------------------------------------------------------------------
__global__ __launch_bounds__(128, 3) void layer_kernel(
    const unsigned int* __restrict__ vin0, const unsigned int* __restrict__ vin1,
    unsigned int* __restrict__ vout0, unsigned int* __restrict__ vout1,
    const unsigned short* __restrict__ MThi, const unsigned short* __restrict__ MTlo,
    const unsigned short* __restrict__ Ahi,  const unsigned short* __restrict__ Alo,
    const unsigned short* __restrict__ cwPhi, const unsigned short* __restrict__ cwPlo,
    const unsigned short* __restrict__ Dhi,   const unsigned short* __restrict__ Dlo,
    const float* __restrict__ cb_0, const float* __restrict__ cb_1,
    float* __restrict__ Ppart, int Lidx)
{
    __shared__ unsigned short Phi[4096];   // block-shared swizzled [c][s64]
    __shared__ unsigned short Plo[4096];

    const int t = threadIdx.x;
    const int bid = blockIdx.x;
    const int br  = bid >> 10;
    const int rem = bid & 1023;
    const int b    = rem >> 4;
    const int tile = rem & 15;
    const int s0   = tile << 6;
    const size_t bS = (size_t)b * SLEN;
    const unsigned int* vin = br ? vin1 : vin0;
    unsigned int* vout      = br ? vout1 : vout0;
    const float* cb = br ? cb_1 : cb_0;
    const int bb = br * 64 + b;
    const int cwbase = (Lidx * 2 + br) * 4096;

    const int lane = t & 63;
    const int w    = t >> 6;          // 0..1: o-half
    const int qr   = lane >> 4;
    const int ln   = lane & 15;

    // ---- preload B fragments for this wave's o-half ----
    s16x8 Bh[2][2], Bl[2][2];
#pragma unroll
    for (int kk = 0; kk < 2; ++kk)
#pragma unroll
        for (int ni = 0; ni < 2; ++ni) {
            const int o = w * 32 + ni * 16 + ln;
            const int boff = cwbase + o * 64 + kk * 32 + qr * 8;
            Bh[kk][ni] = *(const s16x8*)&cwPhi[boff];
            Bl[kk][ni] = *(const s16x8*)&cwPlo[boff];
        }
    s16x8 Dhf[2], Dlf[2];
#pragma unroll
    for (int ni = 0; ni < 2; ++ni) {
        const int o = w * 32 + ni * 16 + ln;
        const int boff = bb * 2048 + o * 32 + qr * 8;
        Dhf[ni] = *(const s16x8*)&Dhi[boff];
        Dlf[ni] = *(const s16x8*)&Dlo[boff];
    }
    float cbv[2];
#pragma unroll
    for (int ni = 0; ni < 2; ++ni) cbv[ni] = cb[w * 32 + ni * 16 + ln];

    // ---- 4 m-tiles ----
#pragma unroll
    for (int mi = 0; mi < 4; ++mi) {
        const int srow = mi * 16 + ln;
        f32x4 acc[2];
        acc[0] = (f32x4){0.f,0.f,0.f,0.f};
        acc[1] = (f32x4){0.f,0.f,0.f,0.f};

#pragma unroll
        for (int kk = 0; kk < 2; ++kk) {
            const size_t aoff = (bS + s0 + srow) * 64 + kk * 32 + qr * 8;
            s16x8 ah, al;
            unpack_frag(&vin[aoff], &ah, &al);
#pragma unroll
            for (int ni = 0; ni < 2; ++ni) {
                acc[ni] = __builtin_amdgcn_mfma_f32_16x16x32_bf16(ah, Bh[kk][ni], acc[ni], 0, 0, 0);
                acc[ni] = __builtin_amdgcn_mfma_f32_16x16x32_bf16(al, Bh[kk][ni], acc[ni], 0, 0, 0);
                acc[ni] = __builtin_amdgcn_mfma_f32_16x16x32_bf16(ah, Bl[kk][ni], acc[ni], 0, 0, 0);
            }
        }
        {
            const size_t aoff = (size_t)(s0 + srow) * 32 + qr * 8;
            s16x8 ah = *(const s16x8*)&MThi[aoff];
            s16x8 al = *(const s16x8*)&MTlo[aoff];
#pragma unroll
            for (int ni = 0; ni < 2; ++ni) {
                acc[ni] = __builtin_amdgcn_mfma_f32_16x16x32_bf16(ah, Dhf[ni], acc[ni], 0, 0, 0);
                acc[ni] = __builtin_amdgcn_mfma_f32_16x16x32_bf16(al, Dhf[ni], acc[ni], 0, 0, 0);
                acc[ni] = __builtin_amdgcn_mfma_f32_16x16x32_bf16(ah, Dlf[ni], acc[ni], 0, 0, 0);
            }
        }
        // epilogue: gelu, split, packed global store + LDS (own c-half)
#pragma unroll
        for (int ni = 0; ni < 2; ++ni) {
            const int o = w * 32 + ni * 16 + ln;
#pragma unroll
            for (int r = 0; r < 4; ++r) {
                const int sl64 = mi * 16 + qr * 4 + r;
                float val = gelu_f(acc[ni][r] + cbv[ni]);
                unsigned short h = f2bf(val);
                unsigned short l = f2bf(val - bf2f(h));
                vout[(bS + s0 + sl64) * 64 + o] =
                    (unsigned int)h | ((unsigned int)l << 16);
                const int a = swz(o, sl64);
                Phi[a] = h;
                Plo[a] = l;
            }
        }
    }

    // ---- proj on own c-half (same-wave LDS RAW: no barrier needed) ----
    f32x4 pacc[2][2];
#pragma unroll
    for (int mt = 0; mt < 2; ++mt)
#pragma unroll
        for (int ni = 0; ni < 2; ++ni) pacc[mt][ni] = (f32x4){0.f,0.f,0.f,0.f};

#pragma unroll
    for (int kk = 0; kk < 2; ++kk) {
        const int bk = kk * 4 + qr;
        s16x8 pah[2], pal[2];
#pragma unroll
        for (int mt = 0; mt < 2; ++mt) {
            const int arow = (mt * 16 + ln) * SLEN + s0 + kk * 32 + qr * 8;
            pah[mt] = *(const s16x8*)&Ahi[arow];
            pal[mt] = *(const s16x8*)&Alo[arow];
        }
#pragma unroll
        for (int ni = 0; ni < 2; ++ni) {
            const int c = w * 32 + ni * 16 + ln;
            const int boff = c * 64 + ((bk ^ (c & 7)) << 3);
            s16x8 bh = *(const s16x8*)&Phi[boff];
            s16x8 bl = *(const s16x8*)&Plo[boff];
#pragma unroll
            for (int mt = 0; mt < 2; ++mt) {
                pacc[mt][ni] = __builtin_amdgcn_mfma_f32_16x16x32_bf16(pah[mt], bh, pacc[mt][ni], 0, 0, 0);
                pacc[mt][ni] = __builtin_amdgcn_mfma_f32_16x16x32_bf16(pal[mt], bh, pacc[mt][ni], 0, 0, 0);
                pacc[mt][ni] = __builtin_amdgcn_mfma_f32_16x16x32_bf16(pah[mt], bl, pacc[mt][ni], 0, 0, 0);
            }
        }
    }
#pragma unroll
    for (int mt = 0; mt < 2; ++mt)
#pragma unroll
        for (int ni = 0; ni < 2; ++ni) {
            const int c = w * 32 + ni * 16 + ln;
#pragma unroll
            for (int r = 0; r < 4; ++r) {
                const int xr = mt * 16 + qr * 4 + r;
                if (xr < 28)
                    Ppart[((size_t)(bb * NT + tile) * 28 + xr) * 64 + c] = pacc[mt][ni][r];
            }
        }
}

// ---------------------------------------------------------------------------
// Head with fused layer 3: 128-thread blocks (2 waves per 64-s tile).
// Packed v input. Phase A per-wave 32-o half -> shared LDS, one barrier.
// Phase B: 64-h half of fc1, gelu*fc2, shfl-reduce, atomicAdd into out.
// ---------------------------------------------------------------------------
__global__ __launch_bounds__(128, 3) void head_kernel(
    const unsigned int* __restrict__ vin0, const unsigned int* __restrict__ vin1,
    const unsigned short* __restrict__ MThi, const unsigned short* __restrict__ MTlo,
    const unsigned short* __restrict__ cwPhi, const unsigned short* __restrict__ cwPlo,
    const unsigned short* __restrict__ Dhi,   const unsigned short* __restrict__ Dlo,
    const float* __restrict__ cb_0, const float* __restrict__ cb_1,
    const unsigned short* __restrict__ w1hi, const unsigned short* __restrict__ w1lo,
    const float* __restrict__ fc1b_0, const float* __restrict__ fc2w_0,
    const float* __restrict__ fc2b_0,
    const float* __restrict__ fc1b_1, const float* __restrict__ fc2w_1,
    const float* __restrict__ fc2b_1,
    float* __restrict__ out)
{
    __shared__ unsigned short Vh[4096];    // block-shared swz2 [s64][c]
    __shared__ unsigned short Vl[4096];

    const int t = threadIdx.x;
    const int bid = blockIdx.x;
    const int br  = bid >> 10;
    const int rem = bid & 1023;
    const int b    = rem >> 4;
    const int tile = rem & 15;
    const int s0   = tile << 6;
    const size_t bS = (size_t)b * SLEN;

    const int lane = t & 63;
    const int w    = t >> 6;          // 0..1
    const int qr   = lane >> 4;
    const int ln   = lane & 15;

    const unsigned int* vin = br ? vin1 : vin0;
    const float* cb   = br ? cb_1 : cb_0;
    const float* fc1b = br ? fc1b_1 : fc1b_0;
    const float* fc2w = br ? fc2w_1 : fc2w_0;
    const float fc2b  = (br ? fc2b_1 : fc2b_0)[0];
    const int bb = br * 64 + b;
    const int cwbase = (3 * 2 + br) * 4096;

    // ---- phase A: layer-3, own 32-o half ----
    {
        s16x8 Bh[2][2], Bl[2][2];
#pragma unroll
        for (int kk = 0; kk < 2; ++kk)
#pragma unroll
            for (int ni = 0; ni < 2; ++ni) {
                const int o = w * 32 + ni * 16 + ln;
                const int boff = cwbase + o * 64 + kk * 32 + qr * 8;
                Bh[kk][ni] = *(const s16x8*)&cwPhi[boff];
                Bl[kk][ni] = *(const s16x8*)&cwPlo[boff];
            }
        s16x8 Dhf[2], Dlf[2];
#pragma unroll
        for (int ni = 0; ni < 2; ++ni) {
            const int o = w * 32 + ni * 16 + ln;
            const int boff = bb * 2048 + o * 32 + qr * 8;
            Dhf[ni] = *(const s16x8*)&Dhi[boff];
            Dlf[ni] = *(const s16x8*)&Dlo[boff];
        }
        float cbv[2];
#pragma unroll
        for (int ni = 0; ni < 2; ++ni) cbv[ni] = cb[w * 32 + ni * 16 + ln];

#pragma unroll
        for (int mi = 0; mi < 4; ++mi) {
            const int srow = mi * 16 + ln;
            f32x4 acc[2];
            acc[0] = (f32x4){0.f,0.f,0.f,0.f};
            acc[1] = (f32x4){0.f,0.f,0.f,0.f};

#pragma unroll
            for (int kk = 0; kk < 2; ++kk) {
                const size_t aoff = (bS + s0 + srow) * 64 + kk * 32 + qr * 8;
                s16x8 ah, al;
                unpack_frag(&vin[aoff], &ah, &al);
#pragma unroll
                for (int ni = 0; ni < 2; ++ni) {
                    acc[ni] = __builtin_amdgcn_mfma_f32_16x16x32_bf16(ah, Bh[kk][ni], acc[ni], 0, 0, 0);
                    acc[ni] = __builtin_amdgcn_mfma_f32_16x16x32_bf16(al, Bh[kk][ni], acc[ni], 0, 0, 0);
                    acc[ni] = __builtin_amdgcn_mfma_f32_16x16x32_bf16(ah, Bl[kk][ni], acc[ni], 0, 0, 0);
                }
            }
            {
                const size_t aoff = (size_t)(s0 + srow) * 32 + qr * 8;
                s16x8 ah = *(const s16x8*)&MThi[aoff];
                s16x8 al = *(const s16x8*)&MTlo[aoff];
#pragma unroll
                for (int ni = 0; ni < 2; ++ni) {
                    acc[ni] = __builtin_amdgcn_mfma_f32_16x16x32_bf16(ah, Dhf[ni], acc[ni], 0, 0, 0);
                    acc[ni] = __builtin_amdgcn_mfma_f32_16x16x32_bf16(al, Dhf[ni], acc[ni], 0, 0, 0);
                    acc[ni] = __builtin_amdgcn_mfma_f32_16x16x32_bf16(ah, Dlf[ni], acc[ni], 0, 0, 0);
                }
            }
#pragma unroll
            for (int ni = 0; ni < 2; ++ni) {
                const int o = w * 32 + ni * 16 + ln;
#pragma unroll
                for (int r = 0; r < 4; ++r) {
                    const int sl64 = mi * 16 + qr * 4 + r;
                    float val = acc[ni][r] + cbv[ni];
                    unsigned short h = f2bf(val);
                    unsigned short l = f2bf(val - bf2f(h));
                    const int a = swz2(sl64, o);
                    Vh[a] = h;
                    Vl[a] = l;
                }
            }
        }
    }
    __syncthreads();

    // ---- phase B: fc1 GEMM, own 64-h half ----
    s16x8 Wh[2][4], Wl[2][4];
#pragma unroll
    for (int kk = 0; kk < 2; ++kk)
#pragma unroll
        for (int ni = 0; ni < 4; ++ni) {
            const int h = w * 64 + ni * 16 + ln;
            const int boff = br * 8192 + h * 64 + kk * 32 + qr * 8;
            Wh[kk][ni] = *(const s16x8*)&w1hi[boff];
            Wl[kk][ni] = *(const s16x8*)&w1lo[boff];
        }
    float b1v[4], w2v[4];
#pragma unroll
    for (int ni = 0; ni < 4; ++ni) {
        b1v[ni] = fc1b[w * 64 + ni * 16 + ln];
        w2v[ni] = fc2w[w * 64 + ni * 16 + ln];
    }

#pragma unroll
    for (int mi = 0; mi < 4; ++mi) {
        f32x4 acc1[4];
#pragma unroll
        for (int ni = 0; ni < 4; ++ni) acc1[ni] = (f32x4){0.f,0.f,0.f,0.f};

#pragma unroll
        for (int kk = 0; kk < 2; ++kk) {
            const int blk = kk * 4 + qr;
            const int sl  = mi * 16 + ln;
            const int a   = sl * 64 + ((blk ^ (sl & 7)) << 3);
            s16x8 ah = *(const s16x8*)&Vh[a];
            s16x8 al = *(const s16x8*)&Vl[a];
#pragma unroll
            for (int ni = 0; ni < 4; ++ni) {
                acc1[ni] = __builtin_amdgcn_mfma_f32_16x16x32_bf16(ah, Wh[kk][ni], acc1[ni], 0, 0, 0);
                acc1[ni] = __builtin_amdgcn_mfma_f32_16x16x32_bf16(al, Wh[kk][ni], acc1[ni], 0, 0, 0);
                acc1[ni] = __builtin_amdgcn_mfma_f32_16x16x32_bf16(ah, Wl[kk][ni], acc1[ni], 0, 0, 0);
            }
        }
        float partial[4] = {0.f, 0.f, 0.f, 0.f};
#pragma unroll
        for (int ni = 0; ni < 4; ++ni) {
#pragma unroll
            for (int r = 0; r < 4; ++r)
                partial[r] += gelu_f(acc1[ni][r] + b1v[ni]) * w2v[ni];
        }
#pragma unroll
        for (int r = 0; r < 4; ++r) {
            partial[r] += __shfl_xor(partial[r], 1, 64);
            partial[r] += __shfl_xor(partial[r], 2, 64);
            partial[r] += __shfl_xor(partial[r], 4, 64);
            partial[r] += __shfl_xor(partial[r], 8, 64);
        }
        if (ln == 0) {
            const float bias = (w == 0) ? fc2b : 0.f;
#pragma unroll
            for (int r = 0; r < 4; ++r)
                atomicAdd(&out[bS + s0 + mi * 16 + qr * 4 + r],
                          partial[r] + bias);
        }
    }
}

// ---------------------------------------------------------------------------
extern "C" void kernel_launch(void* const* d_in, const int* in_sizes, int n_in,
                              void* d_out, int out_size, void* d_ws, size_t ws_size,
                              hipStream_t stream)
{
    const float* x = (const float*)d_in[0];
    const float* P[2][10];
    for (int br = 0; br < 2; ++br)
        for (int k = 0; k < 10; ++k)
            P[br][k] = (const float*)d_in[1 + br * 10 + k];
    // order: fc0_w, fc0_b, wave_w1, wave_w2, cw, cb, fc1_w, fc1_b, fc2_w, fc2_b

    char* p = (char*)d_ws;
    const size_t PL = (size_t)BC * SLEN * 4;   // one packed u32 plane: 16.78 MB
    unsigned int* vplane[4];                   // [br][pingpong]
    for (int i = 0; i < 4; ++i) { vplane[i] = (unsigned int*)p; p += PL; }
    unsigned short* Ahi  = (unsigned short*)p; p += 32 * SLEN * 2;
    unsigned short* Alo  = (unsigned short*)p; p += 32 * SLEN * 2;
    unsigned short* MThi = (unsigned short*)p; p += SLEN * 32 * 2;
    unsigned short* MTlo = (unsigned short*)p; p += SLEN * 32 * 2;
    float* Ppart = (float*)p;                  p += (size_t)128 * NT * 28 * 64 * 4;
    unsigned short* cwPhi = (unsigned short*)p; p += 8 * 4096 * 2;   // [L][br]
    unsigned short* cwPlo = (unsigned short*)p; p += 8 * 4096 * 2;
    unsigned short* Dhi   = (unsigned short*)p; p += (size_t)128 * 2048 * 2;
    unsigned short* Dlo   = (unsigned short*)p; p += (size_t)128 * 2048 * 2;
    unsigned short* w1hi  = (unsigned short*)p; p += 2 * 8192 * 2;
    unsigned short* w1lo  = (unsigned short*)p; p += 2 * 8192 * 2;

    unsigned int *v0a = vplane[0], *v0b = vplane[1];
    unsigned int *v1a = vplane[2], *v1b = vplane[3];

    precompute_kernel<<<1052, 256, 0, stream>>>(Ahi, Alo, MThi, MTlo);

    hipMemsetAsync(d_out, 0, (size_t)out_size * sizeof(float), stream);

    fc0proj_kernel<<<2056, 256, 0, stream>>>(
        x, P[0][0], P[0][1], P[1][0], P[1][1], P[0][6], P[1][6],
        P[0][4], P[1][4],
        Ahi, Alo, v0a, v1a, w1hi, w1lo, cwPhi, cwPlo, Dhi, Dlo, Ppart);

    for (int i = 0; i < 3; ++i) {
        mix_kernel<<<448, 256, 0, stream>>>(
            Ppart,
            P[0][2] + (size_t)i * WCH * WCH * 14, P[0][3] + (size_t)i * WCH * WCH * 14,
            P[1][2] + (size_t)i * WCH * WCH * 14, P[1][3] + (size_t)i * WCH * WCH * 14,
            Dhi, Dlo);
        layer_kernel<<<2048, 128, 0, stream>>>(
            v0a, v1a, v0b, v1b,
            MThi, MTlo, Ahi, Alo, cwPhi, cwPlo, Dhi, Dlo,
            P[0][5] + (size_t)i * WCH, P[1][5] + (size_t)i * WCH,
            Ppart, i);
        unsigned int* tmp;
        tmp = v0a; v0a = v0b; v0b = tmp;
        tmp = v1a; v1a = v1b; v1b = tmp;
    }

    mix_kernel<<<448, 256, 0, stream>>>(
        Ppart,
        P[0][2] + (size_t)3 * WCH * WCH * 14, P[0][3] + (size_t)3 * WCH * WCH * 14,
        P[1][2] + (size_t)3 * WCH * WCH * 14, P[1][3] + (size_t)3 * WCH * WCH * 14,
        Dhi, Dlo);

    head_kernel<<<2048, 128, 0, stream>>>(
        v0a, v1a,
        MThi, MTlo, cwPhi, cwPlo, Dhi, Dlo,
        P[0][5] + (size_t)3 * WCH, P[1][5] + (size_t)3 * WCH,
        w1hi, w1lo,
        P[0][7], P[0][8], P[0][9],
        P[1][7], P[1][8], P[1][9],
        (float*)d_out);
}